// Round 12
// baseline (252.673 us; speedup 1.0000x reference)
//
#include <hip/hip_runtime.h>
#include <hip/hip_bf16.h>

// B=32, N=512, H=8, DH=48, E=384, IN=768, R=16384
// Merged QKV: qkv2[16384][2304] = [qkv_t (1152) | qkv_s (1152)] bf16

typedef __attribute__((ext_vector_type(8))) short s16x8;
typedef __attribute__((ext_vector_type(4))) float f32x4;

__device__ __forceinline__ float lo2f(uint u) { return __uint_as_float(u << 16); }
__device__ __forceinline__ float hi2f(uint u) { return __uint_as_float(u & 0xffff0000u); }
__device__ __forceinline__ ushort f2bu(float f) {
    union { __hip_bfloat16 h; ushort u; } c; c.h = __float2bfloat16(f); return c.u;
}
__device__ __forceinline__ uint pk2(float a, float b) {
    return (uint)f2bu(a) | ((uint)f2bu(b) << 16);
}
__device__ __forceinline__ void gload16(const void* g, void* l) {
    __builtin_amdgcn_global_load_lds((const __attribute__((address_space(1))) void*)g,
                                     (__attribute__((address_space(3))) void*)l, 16, 0, 0);
}

// ---------------------------------------------------------------------------
// fp32 -> bf16 convert, 8 elems/thread
// ---------------------------------------------------------------------------
__global__ __launch_bounds__(256) void convert_bf16(
    const float* __restrict__ in, ushort* __restrict__ out)
{
    const int i = blockIdx.x * 256 + threadIdx.x;
    const float4* p = (const float4*)in + (size_t)i * 2;
    float4 a = p[0], b = p[1];
    uint4 o;
    o.x = pk2(a.x, a.y); o.y = pk2(a.z, a.w);
    o.z = pk2(b.x, b.y); o.w = pk2(b.z, b.w);
    ((uint4*)out)[i] = o;
}

// ---------------------------------------------------------------------------
// concat bias: out[0..1151] = a, out[1152..2303] = b. grid 9 x 256.
// ---------------------------------------------------------------------------
__global__ __launch_bounds__(256) void concat_bias(
    const float* __restrict__ a, const float* __restrict__ b, float* __restrict__ o)
{
    const int i = blockIdx.x * 256 + threadIdx.x;
    o[i] = (i < 1152) ? a[i] : b[i - 1152];
}

// ---------------------------------------------------------------------------
// Transpose+convert: W fp32 [K][N] -> Bt bf16 [noff+n][Kt] (k at koff)
// ---------------------------------------------------------------------------
__global__ __launch_bounds__(256) void transpose_w(
    const float* __restrict__ W, ushort* __restrict__ Bt,
    int K, int N, int Kt, int koff, int noff)
{
    __shared__ float t[32][33];
    const int k0 = blockIdx.x * 32, n0 = blockIdx.y * 32;
    const int r = threadIdx.x >> 3, cq = threadIdx.x & 7;
    float4 v = *(const float4*)(W + (size_t)(k0 + r) * N + n0 + cq * 4);
    t[r][cq * 4 + 0] = v.x; t[r][cq * 4 + 1] = v.y;
    t[r][cq * 4 + 2] = v.z; t[r][cq * 4 + 3] = v.w;
    __syncthreads();
    ushort4 o;
    o.x = f2bu(t[cq * 4 + 0][r]); o.y = f2bu(t[cq * 4 + 1][r]);
    o.z = f2bu(t[cq * 4 + 2][r]); o.w = f2bu(t[cq * 4 + 3][r]);
    *(ushort4*)(Bt + (size_t)(noff + n0 + r) * Kt + koff + k0 + cq * 4) = o;
}

// ---------------------------------------------------------------------------
// 128x128 MFMA GEMM, BK=64, 256 thr = 4 waves (2x2), FINE-PHASED pipeline:
// each K-tile = 2 phases (k-half 0/1). Per phase: stage the NEXT tile's
// matching k-half (4 global_load_lds), counted s_waitcnt vmcnt(8) (3
// half-groups stay in flight), barrier, 8 ds_read_b128, setprio-wrapped
// 16 MFMA, barrier. LDS layout is fragment-contiguous [kh][rowhi][chunk]
// [rowlo] so every wave ds_read is a contiguous 1KB block (0 conflicts,
// no swizzle math). 2 bufs x 32 KB = 64 KB -> 2 blocks/CU.
// C = A[M][K] @ Bt[N][K]^T + bias. Grid (M/128, N/128).
// ---------------------------------------------------------------------------
template<int OUTBF16, int NBIAS>
__global__ __launch_bounds__(256, 2) void gemm128q(
    const ushort* __restrict__ A, const ushort* __restrict__ Bt,
    const float* __restrict__ bias0, const float* __restrict__ bias1,
    void* __restrict__ Cout, int M, int N, int K)
{
    // buf d: A kh0 @ d*16384, A kh1 @ +4096, B kh0 @ +8192, B kh1 @ +12288
    __shared__ ushort smem[32768];
    const int tid = threadIdx.x;
    const int m0 = blockIdx.x << 7;
    const int n0 = blockIdx.y << 7;
    const int lane = tid & 63;
    const int wr = tid >> 7;
    const int wc = (tid >> 6) & 1;
    const int lr = lane & 15;
    const int g = lane >> 4;

    f32x4 acc[4][4];
#pragma unroll
    for (int i = 0; i < 4; ++i)
#pragma unroll
        for (int j = 0; j < 4; ++j) acc[i][j] = (f32x4){0.f, 0.f, 0.f, 0.f};

    // staging geometry: slot s = tid + 256*i (512 slots = 128 rows x 4 chunks)
    // slot -> row = 16*(s>>6) + (s&15), chunk = (s>>4)&3; dest linear (s*16B)
    int rowS[2], chS[2];
#pragma unroll
    for (int i = 0; i < 2; ++i) {
        const int s = tid + 256 * i;
        rowS[i] = ((s >> 6) << 4) | (s & 15);
        chS[i] = (s >> 4) & 3;
    }

    auto stage = [&](const ushort* P, int rbase, int k0, int lb) {
#pragma unroll
        for (int i = 0; i < 2; ++i)
            gload16(P + (size_t)(rbase + rowS[i]) * K + k0 + (chS[i] << 3),
                    &smem[lb + (tid + 256 * i) * 8]);
    };

    // prologue: tile 0, both k-halves (A,B order fixed for vmcnt counting)
    stage(A, m0, 0, 0);
    stage(Bt, n0, 0, 8192);
    stage(A, m0, 32, 4096);
    stage(Bt, n0, 32, 12288);

    const int nt = K >> 6;
    for (int t = 0; t < nt; ++t) {
        const int db = (t & 1) * 16384;
        const int pb = db ^ 16384;
        const bool pf = (t + 1) < nt;
        const int kn = (t + 1) << 6;

        // ================= phase kh = 0 =================
        if (pf) {
            stage(A, m0, kn, pb);
            stage(Bt, n0, kn, pb + 8192);
            asm volatile("s_waitcnt vmcnt(8)" ::: "memory");  // this tile's kh0 landed
        } else {
            asm volatile("s_waitcnt vmcnt(4)" ::: "memory");
        }
        __builtin_amdgcn_sched_barrier(0);
        __builtin_amdgcn_s_barrier();
        __builtin_amdgcn_sched_barrier(0);
        {
            s16x8 af[4], bf[4];
#pragma unroll
            for (int i = 0; i < 4; ++i)
                af[i] = *(const s16x8*)&smem[db + (wr * 4 + i) * 512 + lane * 8];
#pragma unroll
            for (int j = 0; j < 4; ++j)
                bf[j] = *(const s16x8*)&smem[db + 8192 + (wc * 4 + j) * 512 + lane * 8];
            __builtin_amdgcn_s_setprio(1);
#pragma unroll
            for (int i = 0; i < 4; ++i)
#pragma unroll
                for (int j = 0; j < 4; ++j)
                    acc[i][j] = __builtin_amdgcn_mfma_f32_16x16x32_bf16(
                        af[i], bf[j], acc[i][j], 0, 0, 0);
            __builtin_amdgcn_s_setprio(0);
        }
        __builtin_amdgcn_sched_barrier(0);
        __builtin_amdgcn_s_barrier();
        __builtin_amdgcn_sched_barrier(0);

        // ================= phase kh = 1 =================
        if (pf) {
            stage(A, m0, kn + 32, pb + 4096);
            stage(Bt, n0, kn + 32, pb + 12288);
            asm volatile("s_waitcnt vmcnt(8)" ::: "memory");  // this tile's kh1 landed
        } else {
            asm volatile("s_waitcnt vmcnt(0)" ::: "memory");
        }
        __builtin_amdgcn_sched_barrier(0);
        __builtin_amdgcn_s_barrier();
        __builtin_amdgcn_sched_barrier(0);
        {
            s16x8 af[4], bf[4];
#pragma unroll
            for (int i = 0; i < 4; ++i)
                af[i] = *(const s16x8*)&smem[db + 4096 + (wr * 4 + i) * 512 + lane * 8];
#pragma unroll
            for (int j = 0; j < 4; ++j)
                bf[j] = *(const s16x8*)&smem[db + 12288 + (wc * 4 + j) * 512 + lane * 8];
            __builtin_amdgcn_s_setprio(1);
#pragma unroll
            for (int i = 0; i < 4; ++i)
#pragma unroll
                for (int j = 0; j < 4; ++j)
                    acc[i][j] = __builtin_amdgcn_mfma_f32_16x16x32_bf16(
                        af[i], bf[j], acc[i][j], 0, 0, 0);
            __builtin_amdgcn_s_setprio(0);
        }
        __builtin_amdgcn_sched_barrier(0);
        __builtin_amdgcn_s_barrier();
        __builtin_amdgcn_sched_barrier(0);
    }

    // epilogue (r8-proven direct stores)
    const int c0 = n0 + wc * 64 + lr;
    float bsum[4];
#pragma unroll
    for (int j = 0; j < 4; ++j) {
        bsum[j] = bias0[c0 + 16 * j];
        if (NBIAS == 2) bsum[j] += bias1[c0 + 16 * j];
    }
    const int r0 = m0 + wr * 64 + g * 4;
#pragma unroll
    for (int i = 0; i < 4; ++i) {
        const int row = r0 + 16 * i;
#pragma unroll
        for (int j = 0; j < 4; ++j) {
            const int col = c0 + 16 * j;
#pragma unroll
            for (int v = 0; v < 4; ++v) {
                const float val = acc[i][j][v] + bsum[j];
                if (OUTBF16)
                    ((ushort*)Cout)[(size_t)(row + v) * N + col] = f2bu(val);
                else
                    ((float*)Cout)[(size_t)(row + v) * N + col] = val;
            }
        }
    }
}

// ---------------------------------------------------------------------------
// Temporal flash attention, MFMA. Grid 1024 (XCD-remapped), 256 thr = 4 waves.
// qkv2 row stride 2304 ushorts; temporal qkv at cols [0,1152).
// ---------------------------------------------------------------------------
__global__ __launch_bounds__(256, 4) void attn_temporal(
    const ushort* __restrict__ qkv, ushort* __restrict__ xcat)
{
    const int wg = blockIdx.x;
    const int cx = wg & 7, rx = wg >> 3;
    const int id = ((rx >> 2) << 5) + 4 * cx + (rx & 3);
    const int qt = id & 3;
    const int h = (id >> 2) & 7;
    const int b = id >> 5;

    const int tid = threadIdx.x;
    const int w = tid >> 6;
    const int lane = tid & 63;
    const int lr = lane & 15;
    const int g = lane >> 4;

    __shared__ ushort Ks[64 * 64];      // [kv][d], cols 48..63 zero
    __shared__ ushort Vt[48 * 64];      // [d][kv]
    __shared__ ushort Pl[4][32 * 72];
    uint* KsU = (uint*)Ks;
    uint* VtU = (uint*)Vt;

    ((uint4*)Ks)[tid] = make_uint4(0u, 0u, 0u, 0u);
    ((uint4*)Ks)[256 + tid] = make_uint4(0u, 0u, 0u, 0u);
    __syncthreads();

    const uint* qkvu = (const uint*)qkv;
    const int qrow0 = qt * 128 + w * 32;

    s16x8 qf[2][2];
#pragma unroll
    for (int n = 0; n < 2; ++n) {
        const size_t rb = (size_t)(b * 512 + qrow0 + 16 * n + lr) * 2304 + h * 48 + 8 * g;
        qf[n][0] = *(const s16x8*)(qkv + rb);
        qf[n][1] = (g < 2) ? *(const s16x8*)(qkv + rb + 32)
                           : (s16x8){0, 0, 0, 0, 0, 0, 0, 0};
    }

    int p_[3], du_[3];
#pragma unroll
    for (int i = 0; i < 3; ++i) {
        const int idx = tid + 256 * i;
        p_[i] = idx / 24;
        du_[i] = idx % 24;
    }
    uint rk[3][2], rv[3][2];

    auto stage_load = [&](int kv0) {
#pragma unroll
        for (int i = 0; i < 3; ++i) {
            const uint* s0 = qkvu + (size_t)(b * 512 + kv0 + 2 * p_[i]) * 1152
                                  + 192 + h * 24 + du_[i];
            rk[i][0] = s0[0];    rk[i][1] = s0[1152];
            rv[i][0] = s0[192];  rv[i][1] = s0[192 + 1152];
        }
    };
    auto stage_write = [&]() {
#pragma unroll
        for (int i = 0; i < 3; ++i) {
            const int p = p_[i], du = du_[i];
            KsU[(2 * p) * 32 + ((((du >> 2) ^ ((2 * p) & 7)) << 2) | (du & 3))] = rk[i][0];
            KsU[(2 * p + 1) * 32 + ((((du >> 2) ^ ((2 * p + 1) & 7)) << 2) | (du & 3))] = rk[i][1];
            const uint w0 = (rv[i][0] & 0xffffu) | (rv[i][1] << 16);
            const uint w1 = (rv[i][0] >> 16) | (rv[i][1] & 0xffff0000u);
            const int vb = (((p >> 2) ^ (du & 7)) << 2) | (p & 3);
            VtU[(2 * du) * 32 + vb] = w0;
            VtU[(2 * du + 1) * 32 + vb] = w1;
        }
    };

    f32x4 o[2][3];
#pragma unroll
    for (int mq = 0; mq < 2; ++mq)
#pragma unroll
        for (int nd = 0; nd < 3; ++nd) o[mq][nd] = (f32x4){0.f, 0.f, 0.f, 0.f};
    float mrun[2] = {-3.0e38f, -3.0e38f};
    float lsum[2] = {0.f, 0.f};
    float corrv[2];
    const float scale = 0.14433756729740643f; // 1/sqrt(48)

    stage_load(0);
    stage_write();
    __syncthreads();

    for (int t = 0; t < 8; ++t) {
        if (t < 7) stage_load((t + 1) * 64);

        f32x4 sa[4][2];
#pragma unroll
        for (int m = 0; m < 4; ++m)
#pragma unroll
            for (int n = 0; n < 2; ++n) sa[m][n] = (f32x4){0.f, 0.f, 0.f, 0.f};
        __builtin_amdgcn_s_setprio(1);
#pragma unroll
        for (int ks = 0; ks < 2; ++ks)
#pragma unroll
            for (int m = 0; m < 4; ++m) {
                s16x8 kf = *(const s16x8*)&Ks[(16 * m + lr) * 64
                                              + (((g + 4 * ks) ^ (lr & 7)) << 3)];
#pragma unroll
                for (int n = 0; n < 2; ++n)
                    sa[m][n] = __builtin_amdgcn_mfma_f32_16x16x32_bf16(
                        kf, qf[n][ks], sa[m][n], 0, 0, 0);
            }
        __builtin_amdgcn_s_setprio(0);

#pragma unroll
        for (int n = 0; n < 2; ++n) {
            float tmax = -3.0e38f;
#pragma unroll
            for (int m = 0; m < 4; ++m)
#pragma unroll
                for (int v = 0; v < 4; ++v) tmax = fmaxf(tmax, sa[m][n][v]);
            tmax = fmaxf(tmax, __shfl_xor(tmax, 16));
            tmax = fmaxf(tmax, __shfl_xor(tmax, 32));
            float mnew = fmaxf(mrun[n], tmax * scale);
            float corr = __expf(mrun[n] - mnew);
            mrun[n] = mnew;
            float psum = 0.f;
#pragma unroll
            for (int m = 0; m < 4; ++m) {
                float p0 = __expf(fmaf(sa[m][n][0], scale, -mnew));
                float p1 = __expf(fmaf(sa[m][n][1], scale, -mnew));
                float p2 = __expf(fmaf(sa[m][n][2], scale, -mnew));
                float p3 = __expf(fmaf(sa[m][n][3], scale, -mnew));
                psum += (p0 + p1) + (p2 + p3);
                const int base = (16 * n + lr) * 72 + 16 * m + 4 * g;
                *(uint*)&Pl[w][base] = pk2(p0, p1);
                *(uint*)&Pl[w][base + 2] = pk2(p2, p3);
            }
            psum += __shfl_xor(psum, 16);
            psum += __shfl_xor(psum, 32);
            lsum[n] = lsum[n] * corr + psum;
            corrv[n] = corr;
        }

#pragma unroll
        for (int mq = 0; mq < 2; ++mq)
#pragma unroll
            for (int nd = 0; nd < 3; ++nd)
#pragma unroll
                for (int v = 0; v < 4; ++v) o[mq][nd][v] *= corrv[mq];

        __builtin_amdgcn_s_setprio(1);
#pragma unroll
        for (int ks = 0; ks < 2; ++ks) {
            s16x8 vf[3];
#pragma unroll
            for (int nd = 0; nd < 3; ++nd)
                vf[nd] = *(const s16x8*)&Vt[(16 * nd + lr) * 64
                                            + (((g + 4 * ks) ^ (lr >> 1)) << 3)];
#pragma unroll
            for (int mq = 0; mq < 2; ++mq) {
                s16x8 pf = *(const s16x8*)&Pl[w][(16 * mq + lr) * 72 + 8 * g + 32 * ks];
#pragma unroll
                for (int nd = 0; nd < 3; ++nd)
                    o[mq][nd] = __builtin_amdgcn_mfma_f32_16x16x32_bf16(
                        vf[nd], pf, o[mq][nd], 0, 0, 0);
            }
        }
        __builtin_amdgcn_s_setprio(0);
        __syncthreads();
        if (t < 7) stage_write();
        __syncthreads();
    }

#pragma unroll
    for (int mq = 0; mq < 2; ++mq) {
        const float li = 1.f / lsum[mq];
        const int qrow = qrow0 + 16 * mq + lr;
        ushort* dst = xcat + (size_t)(b * 512 + qrow) * 768 + h * 48;
#pragma unroll
        for (int nd = 0; nd < 3; ++nd) {
            uint2 o2;
            o2.x = pk2(o[mq][nd][0] * li, o[mq][nd][1] * li);
            o2.y = pk2(o[mq][nd][2] * li, o[mq][nd][3] * li);
            *(uint2*)(dst + 16 * nd + 4 * g) = o2;
        }
    }
}

// ---------------------------------------------------------------------------
// Spatial attention (unscaled). One block per g. 192 thr = 8h x 24t.
// Spatial qkv at ushort cols [1152, 2304) of qkv2.
// ---------------------------------------------------------------------------
__global__ __launch_bounds__(192) void attn_spatial(
    const ushort* __restrict__ qkv, ushort* __restrict__ xcat)
{
    const int g = blockIdx.x;
    __shared__ float row[1152];
    const uint* qkvu = (const uint*)qkv;
#pragma unroll
    for (int i = 0; i < 3; ++i) {
        int idx = threadIdx.x + 192 * i;
        uint u = qkvu[(size_t)g * 1152 + 576 + idx];
        row[2 * idx] = lo2f(u); row[2 * idx + 1] = hi2f(u);
    }
    __syncthreads();

    const int h = threadIdx.x / 24;
    const int t = threadIdx.x % 24;
    const float* q = &row[h * 48];
    const float* k = &row[384 + h * 48];
    const float* v = &row[768 + h * 48];
    const float q0 = q[t], q1 = q[24 + t];

    float s[24];
    float mx = -3.0e38f;
#pragma unroll
    for (int u = 0; u < 24; ++u) {
        s[u] = q0 * k[u] + q1 * k[24 + u];
        mx = fmaxf(mx, s[u]);
    }
    float l = 0.f;
#pragma unroll
    for (int u = 0; u < 24; ++u) { s[u] = __expf(s[u] - mx); l += s[u]; }
    const float inv = 1.f / l;
    float o0 = 0.f, o1 = 0.f;
#pragma unroll
    for (int u = 0; u < 24; ++u) {
        o0 = fmaf(s[u], v[u], o0);
        o1 = fmaf(s[u], v[24 + u], o1);
    }
    ushort* dst = xcat + (size_t)g * 768 + 384 + h * 48;
    dst[t] = f2bu(o0 * inv);
    dst[24 + t] = f2bu(o1 * inv);
}

// ---------------------------------------------------------------------------
// Column partial sums (bf16 in, fp32 out). grid (32,3,8).
// ---------------------------------------------------------------------------
__global__ __launch_bounds__(256) void colsum(
    const ushort* __restrict__ xcat, float* __restrict__ partial)
{
    const int b = blockIdx.x, ch = blockIdx.y, part = blockIdx.z;
    const int e = ch * 256 + threadIdx.x;
    const int n0 = part * 64;
    float s = 0.f;
    for (int n = 0; n < 64; ++n)
        s += __uint_as_float((uint)xcat[((size_t)(b * 512 + n0 + n)) * 768 + e] << 16);
    partial[((size_t)(b * 8 + part)) * 768 + e] = s;
}

// ---------------------------------------------------------------------------
// Gating, parallel. grid (32 b, 6 j-tiles of 128), 256 thr.
// ---------------------------------------------------------------------------
__global__ __launch_bounds__(256) void alpha_gate(
    const float* __restrict__ partial, const float* __restrict__ Wts,
    const float* __restrict__ bts, float* __restrict__ gate)
{
    const int b = blockIdx.x;
    const int j0 = blockIdx.y * 128;
    __shared__ float av[768];
    __shared__ float psum[2][128];

    for (int i = threadIdx.x; i < 768; i += 256) {
        float s = 0.f;
#pragma unroll
        for (int p = 0; p < 8; ++p)
            s += partial[((size_t)(b * 8 + p)) * 768 + i];
        av[i] = s * (1.0f / 512.0f);
    }
    __syncthreads();

    const int jl = threadIdx.x & 127;
    const int seg = threadIdx.x >> 7;
    const int j = j0 + jl;
    const float* Wp = Wts + (size_t)(seg * 384) * 768 + j;
    const float* avp = av + seg * 384;
    float a0 = 0.f, a1 = 0.f, a2 = 0.f, a3 = 0.f;
    float a4 = 0.f, a5 = 0.f, a6 = 0.f, a7 = 0.f;
#pragma unroll 4
    for (int k = 0; k < 384; k += 8) {
        a0 = fmaf(avp[k + 0], Wp[(size_t)(k + 0) * 768], a0);
        a1 = fmaf(avp[k + 1], Wp[(size_t)(k + 1) * 768], a1);
        a2 = fmaf(avp[k + 2], Wp[(size_t)(k + 2) * 768], a2);
        a3 = fmaf(avp[k + 3], Wp[(size_t)(k + 3) * 768], a3);
        a4 = fmaf(avp[k + 4], Wp[(size_t)(k + 4) * 768], a4);
        a5 = fmaf(avp[k + 5], Wp[(size_t)(k + 5) * 768], a5);
        a6 = fmaf(avp[k + 6], Wp[(size_t)(k + 6) * 768], a6);
        a7 = fmaf(avp[k + 7], Wp[(size_t)(k + 7) * 768], a7);
    }
    psum[seg][jl] = ((a0 + a1) + (a2 + a3)) + ((a4 + a5) + (a6 + a7));
    __syncthreads();

    if (threadIdx.x < 128)
        av[threadIdx.x] = psum[0][threadIdx.x] + psum[1][threadIdx.x]
                        + bts[j0 + threadIdx.x];
    __syncthreads();
    if (threadIdx.x < 64) {
        const int e = (j0 >> 1) + threadIdx.x;
        float x0 = av[2 * threadIdx.x], x1 = av[2 * threadIdx.x + 1];
        float m = fmaxf(x0, x1);
        float e0 = __expf(x0 - m), e1 = __expf(x1 - m);
        float inv = 1.f / (e0 + e1);
        gate[(size_t)b * 768 + e] = e0 * inv;
        gate[(size_t)b * 768 + 384 + e] = e1 * inv;
    }
}

// ---------------------------------------------------------------------------
// xg = bf16(xcat * gate[b]), 8 elems/thread
// ---------------------------------------------------------------------------
__global__ __launch_bounds__(256) void gate_mul(
    const ushort* __restrict__ xcat, const float* __restrict__ gate,
    ushort* __restrict__ xg)
{
    const int i = blockIdx.x * 256 + threadIdx.x;
    const int m = i / 96;
    const int k = (i % 96) * 8;
    const int b = m >> 9;
    uint4 u = ((const uint4*)xcat)[i];
    const float* g = gate + (size_t)b * 768 + k;
    float4 g0 = *(const float4*)g;
    float4 g1 = *(const float4*)(g + 4);
    uint4 o;
    o.x = pk2(lo2f(u.x) * g0.x, hi2f(u.x) * g0.y);
    o.y = pk2(lo2f(u.y) * g0.z, hi2f(u.y) * g0.w);
    o.z = pk2(lo2f(u.z) * g1.x, hi2f(u.z) * g1.y);
    o.w = pk2(lo2f(u.w) * g1.z, hi2f(u.w) * g1.w);
    ((uint4*)xg)[i] = o;
}

// ---------------------------------------------------------------------------
extern "C" void kernel_launch(void* const* d_in, const int* in_sizes, int n_in,
                              void* d_out, int out_size, void* d_ws, size_t ws_size,
                              hipStream_t stream)
{
    const float* x      = (const float*)d_in[0];
    const float* Wqkv_t = (const float*)d_in[1];
    const float* bqkv_t = (const float*)d_in[2];
    const float* Wqkv_s = (const float*)d_in[3];
    const float* bqkv_s = (const float*)d_in[4];
    const float* Wts    = (const float*)d_in[5];
    const float* bts    = (const float*)d_in[6];
    const float* Wfc_t  = (const float*)d_in[7];
    const float* bfc_t  = (const float*)d_in[8];
    const float* Wfc_s  = (const float*)d_in[9];
    const float* bfc_s  = (const float*)d_in[10];
    float* out = (float*)d_out;

    char* w = (char*)d_ws;
    ushort* qkv2   = (ushort*)(w);                 // 16384*2304 bf16 = 75,497,472 B
    ushort* xg     = qkv2;                         // reuse (dead after attn)
    ushort* xcat   = (ushort*)(w + 75497472);      // 16384*768 bf16  = 25,165,824 B
    ushort* xb     = (ushort*)(w + 100663296);     // 16384*768 bf16  = 25,165,824 B
    ushort* wbuf   = (ushort*)(w + 125829120);     // 2304*768 bf16   =  3,538,944 B
    ushort* wbuf2  = (ushort*)(w + 129368064);     // 768*768 bf16    =  1,179,648 B
    float*  partial= (float*)(w + 130547712);      // 32*8*768 f32    =    786,432 B
    float*  gate   = (float*)(w + 131334144);      // 32*768 f32      =     98,304 B
    float*  bias2  = (float*)(w + 131432448);      // 2304 f32

    const dim3 blk256(256);

    // prep: x -> bf16; merged QKV weights wbuf[2304][768]; bias concat
    convert_bf16<<<dim3(6144), blk256, 0, stream>>>(x, xb);
    concat_bias<<<dim3(9), blk256, 0, stream>>>(bqkv_t, bqkv_s, bias2);
    transpose_w<<<dim3(24, 36), blk256, 0, stream>>>(Wqkv_t, wbuf, 768, 1152, 768, 0, 0);
    transpose_w<<<dim3(24, 36), blk256, 0, stream>>>(Wqkv_s, wbuf, 768, 1152, 768, 0, 1152);

    // merged QKV GEMM: [16384 x 2304] = xb @ wbuf^T + bias2
    gemm128q<1, 1><<<dim3(128, 18), blk256, 0, stream>>>(
        xb, wbuf, bias2, nullptr, qkv2, 16384, 2304, 768);

    attn_temporal<<<dim3(1024), blk256, 0, stream>>>(qkv2, xcat);
    attn_spatial<<<dim3(16384), dim3(192), 0, stream>>>(qkv2, xcat);

    // gating
    colsum<<<dim3(32, 3, 8), blk256, 0, stream>>>(xcat, partial);
    alpha_gate<<<dim3(32, 6), blk256, 0, stream>>>(partial, Wts, bts, gate);
    gate_mul<<<dim3(6144), blk256, 0, stream>>>(xcat, gate, xg);

    // final GEMM: wbuf2 = [Wfc_t; Wfc_s]^T -> [768 n][768 k]
    transpose_w<<<dim3(12, 24), blk256, 0, stream>>>(Wfc_t, wbuf2, 384, 768, 768, 0, 0);
    transpose_w<<<dim3(12, 24), blk256, 0, stream>>>(Wfc_s, wbuf2, 384, 768, 768, 384, 0);
    gemm128q<0, 2><<<dim3(128, 6), blk256, 0, stream>>>(
        xg, wbuf2, bfc_t, bfc_s, out, 16384, 768, 768);
}

// Round 13
// 252.463 us; speedup vs baseline: 1.0008x; 1.0008x over previous
//
#include <hip/hip_runtime.h>
#include <hip/hip_bf16.h>

// B=32, N=512, H=8, DH=48, E=384, IN=768, R=16384
// Merged QKV: qkv2[16384][2304] = [qkv_t (1152) | qkv_s (1152)] bf16

typedef __attribute__((ext_vector_type(8))) short s16x8;
typedef __attribute__((ext_vector_type(4))) float f32x4;

__device__ __forceinline__ float lo2f(uint u) { return __uint_as_float(u << 16); }
__device__ __forceinline__ float hi2f(uint u) { return __uint_as_float(u & 0xffff0000u); }
__device__ __forceinline__ ushort f2bu(float f) {
    union { __hip_bfloat16 h; ushort u; } c; c.h = __float2bfloat16(f); return c.u;
}
__device__ __forceinline__ uint pk2(float a, float b) {
    return (uint)f2bu(a) | ((uint)f2bu(b) << 16);
}
__device__ __forceinline__ void gload16(const void* g, void* l) {
    __builtin_amdgcn_global_load_lds((const __attribute__((address_space(1))) void*)g,
                                     (__attribute__((address_space(3))) void*)l, 16, 0, 0);
}

// ---------------------------------------------------------------------------
// fp32 -> bf16 convert, 8 elems/thread
// ---------------------------------------------------------------------------
__global__ __launch_bounds__(256) void convert_bf16(
    const float* __restrict__ in, ushort* __restrict__ out)
{
    const int i = blockIdx.x * 256 + threadIdx.x;
    const float4* p = (const float4*)in + (size_t)i * 2;
    float4 a = p[0], b = p[1];
    uint4 o;
    o.x = pk2(a.x, a.y); o.y = pk2(a.z, a.w);
    o.z = pk2(b.x, b.y); o.w = pk2(b.z, b.w);
    ((uint4*)out)[i] = o;
}

// ---------------------------------------------------------------------------
// concat bias: out[0..1151] = a, out[1152..2303] = b. grid 9 x 256.
// ---------------------------------------------------------------------------
__global__ __launch_bounds__(256) void concat_bias(
    const float* __restrict__ a, const float* __restrict__ b, float* __restrict__ o)
{
    const int i = blockIdx.x * 256 + threadIdx.x;
    o[i] = (i < 1152) ? a[i] : b[i - 1152];
}

// ---------------------------------------------------------------------------
// Transpose+convert: W fp32 [K][N] -> Bt bf16 [noff+n][Kt] (k at koff)
// ---------------------------------------------------------------------------
__global__ __launch_bounds__(256) void transpose_w(
    const float* __restrict__ W, ushort* __restrict__ Bt,
    int K, int N, int Kt, int koff, int noff)
{
    __shared__ float t[32][33];
    const int k0 = blockIdx.x * 32, n0 = blockIdx.y * 32;
    const int r = threadIdx.x >> 3, cq = threadIdx.x & 7;
    float4 v = *(const float4*)(W + (size_t)(k0 + r) * N + n0 + cq * 4);
    t[r][cq * 4 + 0] = v.x; t[r][cq * 4 + 1] = v.y;
    t[r][cq * 4 + 2] = v.z; t[r][cq * 4 + 3] = v.w;
    __syncthreads();
    ushort4 o;
    o.x = f2bu(t[cq * 4 + 0][r]); o.y = f2bu(t[cq * 4 + 1][r]);
    o.z = f2bu(t[cq * 4 + 2][r]); o.w = f2bu(t[cq * 4 + 3][r]);
    *(ushort4*)(Bt + (size_t)(noff + n0 + r) * Kt + koff + k0 + cq * 4) = o;
}

// ---------------------------------------------------------------------------
// 128x128 MFMA GEMM, BK=32, 256 thr = 4 waves (2x2), counted-vmcnt pipeline
// (r8's exact sync skeleton at half the K-tile): tile t+1's 4 global_load_lds
// stay in flight across both barriers (vmcnt(4)); 2 LDS bufs x 16 KB = 32 KB
// -> 4-5 blocks/CU (16-20 waves: cross-block overlap hides barrier drains).
// LDS is fragment-contiguous (stage slot s -> row 16(s>>6)+(s&15), chunk
// (s>>4)&3; dest linear): every wave ds_read_b128 is a contiguous 1KB block,
// zero bank conflicts. C = A[M][K] @ Bt[N][K]^T + bias. Grid (M/128, N/128).
// ---------------------------------------------------------------------------
template<int OUTBF16, int NBIAS>
__global__ __launch_bounds__(256, 4) void gemm128s(
    const ushort* __restrict__ A, const ushort* __restrict__ Bt,
    const float* __restrict__ bias0, const float* __restrict__ bias1,
    void* __restrict__ Cout, int M, int N, int K)
{
    // buf d (d=0,1): A frags @ d*8192, B frags @ d*8192+4096 (ushort idx)
    __shared__ ushort smem[16384];
    const int tid = threadIdx.x;
    const int m0 = blockIdx.x << 7;
    const int n0 = blockIdx.y << 7;
    const int lane = tid & 63;
    const int wr = tid >> 7;
    const int wc = (tid >> 6) & 1;
    const int lr = lane & 15;
    const int g = lane >> 4;

    f32x4 acc[4][4];
#pragma unroll
    for (int i = 0; i < 4; ++i)
#pragma unroll
        for (int j = 0; j < 4; ++j) acc[i][j] = (f32x4){0.f, 0.f, 0.f, 0.f};

    // staging geometry: 512 slots/operand; slot s -> row 16(s>>6)+(s&15),
    // k-chunk (s>>4)&3 (16B). Dest linear (slot*16B) = fragment-contiguous.
    int rowS[2], chS[2];
#pragma unroll
    for (int i = 0; i < 2; ++i) {
        const int s = tid + 256 * i;
        rowS[i] = ((s >> 6) << 4) | (s & 15);
        chS[i] = (s >> 4) & 3;
    }

    auto stage = [&](int buf, int k0) {
        ushort* dA = &smem[buf * 8192];
        ushort* dB = &smem[buf * 8192 + 4096];
#pragma unroll
        for (int i = 0; i < 2; ++i)
            gload16(A + (size_t)(m0 + rowS[i]) * K + k0 + (chS[i] << 3),
                    dA + (tid + 256 * i) * 8);
#pragma unroll
        for (int i = 0; i < 2; ++i)
            gload16(Bt + (size_t)(n0 + rowS[i]) * K + k0 + (chS[i] << 3),
                    dB + (tid + 256 * i) * 8);
    };

    stage(0, 0);                      // 4 loads in flight
    const int nt = K >> 5;
    for (int t = 0; t < nt; ++t) {
        const int cur = t & 1;
        if (t + 1 < nt) {
            stage(cur ^ 1, (t + 1) << 5);                    // +4 (8 total)
            asm volatile("s_waitcnt vmcnt(4)" ::: "memory");  // tile t landed;
        } else {                                              // t+1 in flight
            asm volatile("s_waitcnt vmcnt(0)" ::: "memory");
        }
        __builtin_amdgcn_sched_barrier(0);
        __builtin_amdgcn_s_barrier();
        __builtin_amdgcn_sched_barrier(0);

        const ushort* As = &smem[cur * 8192];
        const ushort* Bs = &smem[cur * 8192 + 4096];
        s16x8 af[4], bf[4];
#pragma unroll
        for (int i = 0; i < 4; ++i)
            af[i] = *(const s16x8*)&As[(wr * 4 + i) * 512 + lane * 8];
#pragma unroll
        for (int j = 0; j < 4; ++j)
            bf[j] = *(const s16x8*)&Bs[(wc * 4 + j) * 512 + lane * 8];
        __builtin_amdgcn_s_setprio(1);
#pragma unroll
        for (int i = 0; i < 4; ++i)
#pragma unroll
            for (int j = 0; j < 4; ++j)
                acc[i][j] = __builtin_amdgcn_mfma_f32_16x16x32_bf16(
                    af[i], bf[j], acc[i][j], 0, 0, 0);
        __builtin_amdgcn_s_setprio(0);
        __builtin_amdgcn_sched_barrier(0);
        __builtin_amdgcn_s_barrier();   // WAR: next iter DMAs into buf cur
    }

    // epilogue (r8-proven direct stores)
    const int c0 = n0 + wc * 64 + lr;
    float bsum[4];
#pragma unroll
    for (int j = 0; j < 4; ++j) {
        bsum[j] = bias0[c0 + 16 * j];
        if (NBIAS == 2) bsum[j] += bias1[c0 + 16 * j];
    }
    const int r0 = m0 + wr * 64 + g * 4;
#pragma unroll
    for (int i = 0; i < 4; ++i) {
        const int row = r0 + 16 * i;
#pragma unroll
        for (int j = 0; j < 4; ++j) {
            const int col = c0 + 16 * j;
#pragma unroll
            for (int v = 0; v < 4; ++v) {
                const float val = acc[i][j][v] + bsum[j];
                if (OUTBF16)
                    ((ushort*)Cout)[(size_t)(row + v) * N + col] = f2bu(val);
                else
                    ((float*)Cout)[(size_t)(row + v) * N + col] = val;
            }
        }
    }
}

// ---------------------------------------------------------------------------
// Temporal flash attention, MFMA. Grid 1024 (XCD-remapped), 256 thr = 4 waves.
// qkv2 row stride 2304 ushorts; temporal qkv at cols [0,1152).
// ---------------------------------------------------------------------------
__global__ __launch_bounds__(256, 4) void attn_temporal(
    const ushort* __restrict__ qkv, ushort* __restrict__ xcat)
{
    const int wg = blockIdx.x;
    const int cx = wg & 7, rx = wg >> 3;
    const int id = ((rx >> 2) << 5) + 4 * cx + (rx & 3);
    const int qt = id & 3;
    const int h = (id >> 2) & 7;
    const int b = id >> 5;

    const int tid = threadIdx.x;
    const int w = tid >> 6;
    const int lane = tid & 63;
    const int lr = lane & 15;
    const int g = lane >> 4;

    __shared__ ushort Ks[64 * 64];      // [kv][d], cols 48..63 zero
    __shared__ ushort Vt[48 * 64];      // [d][kv]
    __shared__ ushort Pl[4][32 * 72];
    uint* KsU = (uint*)Ks;
    uint* VtU = (uint*)Vt;

    ((uint4*)Ks)[tid] = make_uint4(0u, 0u, 0u, 0u);
    ((uint4*)Ks)[256 + tid] = make_uint4(0u, 0u, 0u, 0u);
    __syncthreads();

    const uint* qkvu = (const uint*)qkv;
    const int qrow0 = qt * 128 + w * 32;

    s16x8 qf[2][2];
#pragma unroll
    for (int n = 0; n < 2; ++n) {
        const size_t rb = (size_t)(b * 512 + qrow0 + 16 * n + lr) * 2304 + h * 48 + 8 * g;
        qf[n][0] = *(const s16x8*)(qkv + rb);
        qf[n][1] = (g < 2) ? *(const s16x8*)(qkv + rb + 32)
                           : (s16x8){0, 0, 0, 0, 0, 0, 0, 0};
    }

    int p_[3], du_[3];
#pragma unroll
    for (int i = 0; i < 3; ++i) {
        const int idx = tid + 256 * i;
        p_[i] = idx / 24;
        du_[i] = idx % 24;
    }
    uint rk[3][2], rv[3][2];

    auto stage_load = [&](int kv0) {
#pragma unroll
        for (int i = 0; i < 3; ++i) {
            const uint* s0 = qkvu + (size_t)(b * 512 + kv0 + 2 * p_[i]) * 1152
                                  + 192 + h * 24 + du_[i];
            rk[i][0] = s0[0];    rk[i][1] = s0[1152];
            rv[i][0] = s0[192];  rv[i][1] = s0[192 + 1152];
        }
    };
    auto stage_write = [&]() {
#pragma unroll
        for (int i = 0; i < 3; ++i) {
            const int p = p_[i], du = du_[i];
            KsU[(2 * p) * 32 + ((((du >> 2) ^ ((2 * p) & 7)) << 2) | (du & 3))] = rk[i][0];
            KsU[(2 * p + 1) * 32 + ((((du >> 2) ^ ((2 * p + 1) & 7)) << 2) | (du & 3))] = rk[i][1];
            const uint w0 = (rv[i][0] & 0xffffu) | (rv[i][1] << 16);
            const uint w1 = (rv[i][0] >> 16) | (rv[i][1] & 0xffff0000u);
            const int vb = (((p >> 2) ^ (du & 7)) << 2) | (p & 3);
            VtU[(2 * du) * 32 + vb] = w0;
            VtU[(2 * du + 1) * 32 + vb] = w1;
        }
    };

    f32x4 o[2][3];
#pragma unroll
    for (int mq = 0; mq < 2; ++mq)
#pragma unroll
        for (int nd = 0; nd < 3; ++nd) o[mq][nd] = (f32x4){0.f, 0.f, 0.f, 0.f};
    float mrun[2] = {-3.0e38f, -3.0e38f};
    float lsum[2] = {0.f, 0.f};
    float corrv[2];
    const float scale = 0.14433756729740643f; // 1/sqrt(48)

    stage_load(0);
    stage_write();
    __syncthreads();

    for (int t = 0; t < 8; ++t) {
        if (t < 7) stage_load((t + 1) * 64);

        f32x4 sa[4][2];
#pragma unroll
        for (int m = 0; m < 4; ++m)
#pragma unroll
            for (int n = 0; n < 2; ++n) sa[m][n] = (f32x4){0.f, 0.f, 0.f, 0.f};
        __builtin_amdgcn_s_setprio(1);
#pragma unroll
        for (int ks = 0; ks < 2; ++ks)
#pragma unroll
            for (int m = 0; m < 4; ++m) {
                s16x8 kf = *(const s16x8*)&Ks[(16 * m + lr) * 64
                                              + (((g + 4 * ks) ^ (lr & 7)) << 3)];
#pragma unroll
                for (int n = 0; n < 2; ++n)
                    sa[m][n] = __builtin_amdgcn_mfma_f32_16x16x32_bf16(
                        kf, qf[n][ks], sa[m][n], 0, 0, 0);
            }
        __builtin_amdgcn_s_setprio(0);

#pragma unroll
        for (int n = 0; n < 2; ++n) {
            float tmax = -3.0e38f;
#pragma unroll
            for (int m = 0; m < 4; ++m)
#pragma unroll
                for (int v = 0; v < 4; ++v) tmax = fmaxf(tmax, sa[m][n][v]);
            tmax = fmaxf(tmax, __shfl_xor(tmax, 16));
            tmax = fmaxf(tmax, __shfl_xor(tmax, 32));
            float mnew = fmaxf(mrun[n], tmax * scale);
            float corr = __expf(mrun[n] - mnew);
            mrun[n] = mnew;
            float psum = 0.f;
#pragma unroll
            for (int m = 0; m < 4; ++m) {
                float p0 = __expf(fmaf(sa[m][n][0], scale, -mnew));
                float p1 = __expf(fmaf(sa[m][n][1], scale, -mnew));
                float p2 = __expf(fmaf(sa[m][n][2], scale, -mnew));
                float p3 = __expf(fmaf(sa[m][n][3], scale, -mnew));
                psum += (p0 + p1) + (p2 + p3);
                const int base = (16 * n + lr) * 72 + 16 * m + 4 * g;
                *(uint*)&Pl[w][base] = pk2(p0, p1);
                *(uint*)&Pl[w][base + 2] = pk2(p2, p3);
            }
            psum += __shfl_xor(psum, 16);
            psum += __shfl_xor(psum, 32);
            lsum[n] = lsum[n] * corr + psum;
            corrv[n] = corr;
        }

#pragma unroll
        for (int mq = 0; mq < 2; ++mq)
#pragma unroll
            for (int nd = 0; nd < 3; ++nd)
#pragma unroll
                for (int v = 0; v < 4; ++v) o[mq][nd][v] *= corrv[mq];

        __builtin_amdgcn_s_setprio(1);
#pragma unroll
        for (int ks = 0; ks < 2; ++ks) {
            s16x8 vf[3];
#pragma unroll
            for (int nd = 0; nd < 3; ++nd)
                vf[nd] = *(const s16x8*)&Vt[(16 * nd + lr) * 64
                                            + (((g + 4 * ks) ^ (lr >> 1)) << 3)];
#pragma unroll
            for (int mq = 0; mq < 2; ++mq) {
                s16x8 pf = *(const s16x8*)&Pl[w][(16 * mq + lr) * 72 + 8 * g + 32 * ks];
#pragma unroll
                for (int nd = 0; nd < 3; ++nd)
                    o[mq][nd] = __builtin_amdgcn_mfma_f32_16x16x32_bf16(
                        vf[nd], pf, o[mq][nd], 0, 0, 0);
            }
        }
        __builtin_amdgcn_s_setprio(0);
        __syncthreads();
        if (t < 7) stage_write();
        __syncthreads();
    }

#pragma unroll
    for (int mq = 0; mq < 2; ++mq) {
        const float li = 1.f / lsum[mq];
        const int qrow = qrow0 + 16 * mq + lr;
        ushort* dst = xcat + (size_t)(b * 512 + qrow) * 768 + h * 48;
#pragma unroll
        for (int nd = 0; nd < 3; ++nd) {
            uint2 o2;
            o2.x = pk2(o[mq][nd][0] * li, o[mq][nd][1] * li);
            o2.y = pk2(o[mq][nd][2] * li, o[mq][nd][3] * li);
            *(uint2*)(dst + 16 * nd + 4 * g) = o2;
        }
    }
}

// ---------------------------------------------------------------------------
// Spatial attention (unscaled). One block per g. 192 thr = 8h x 24t.
// Spatial qkv at ushort cols [1152, 2304) of qkv2.
// ---------------------------------------------------------------------------
__global__ __launch_bounds__(192) void attn_spatial(
    const ushort* __restrict__ qkv, ushort* __restrict__ xcat)
{
    const int g = blockIdx.x;
    __shared__ float row[1152];
    const uint* qkvu = (const uint*)qkv;
#pragma unroll
    for (int i = 0; i < 3; ++i) {
        int idx = threadIdx.x + 192 * i;
        uint u = qkvu[(size_t)g * 1152 + 576 + idx];
        row[2 * idx] = lo2f(u); row[2 * idx + 1] = hi2f(u);
    }
    __syncthreads();

    const int h = threadIdx.x / 24;
    const int t = threadIdx.x % 24;
    const float* q = &row[h * 48];
    const float* k = &row[384 + h * 48];
    const float* v = &row[768 + h * 48];
    const float q0 = q[t], q1 = q[24 + t];

    float s[24];
    float mx = -3.0e38f;
#pragma unroll
    for (int u = 0; u < 24; ++u) {
        s[u] = q0 * k[u] + q1 * k[24 + u];
        mx = fmaxf(mx, s[u]);
    }
    float l = 0.f;
#pragma unroll
    for (int u = 0; u < 24; ++u) { s[u] = __expf(s[u] - mx); l += s[u]; }
    const float inv = 1.f / l;
    float o0 = 0.f, o1 = 0.f;
#pragma unroll
    for (int u = 0; u < 24; ++u) {
        o0 = fmaf(s[u], v[u], o0);
        o1 = fmaf(s[u], v[24 + u], o1);
    }
    ushort* dst = xcat + (size_t)g * 768 + 384 + h * 48;
    dst[t] = f2bu(o0 * inv);
    dst[24 + t] = f2bu(o1 * inv);
}

// ---------------------------------------------------------------------------
// Column partial sums (bf16 in, fp32 out). grid (32,3,8).
// ---------------------------------------------------------------------------
__global__ __launch_bounds__(256) void colsum(
    const ushort* __restrict__ xcat, float* __restrict__ partial)
{
    const int b = blockIdx.x, ch = blockIdx.y, part = blockIdx.z;
    const int e = ch * 256 + threadIdx.x;
    const int n0 = part * 64;
    float s = 0.f;
    for (int n = 0; n < 64; ++n)
        s += __uint_as_float((uint)xcat[((size_t)(b * 512 + n0 + n)) * 768 + e] << 16);
    partial[((size_t)(b * 8 + part)) * 768 + e] = s;
}

// ---------------------------------------------------------------------------
// Gating, parallel. grid (32 b, 6 j-tiles of 128), 256 thr.
// ---------------------------------------------------------------------------
__global__ __launch_bounds__(256) void alpha_gate(
    const float* __restrict__ partial, const float* __restrict__ Wts,
    const float* __restrict__ bts, float* __restrict__ gate)
{
    const int b = blockIdx.x;
    const int j0 = blockIdx.y * 128;
    __shared__ float av[768];
    __shared__ float psum[2][128];

    for (int i = threadIdx.x; i < 768; i += 256) {
        float s = 0.f;
#pragma unroll
        for (int p = 0; p < 8; ++p)
            s += partial[((size_t)(b * 8 + p)) * 768 + i];
        av[i] = s * (1.0f / 512.0f);
    }
    __syncthreads();

    const int jl = threadIdx.x & 127;
    const int seg = threadIdx.x >> 7;
    const int j = j0 + jl;
    const float* Wp = Wts + (size_t)(seg * 384) * 768 + j;
    const float* avp = av + seg * 384;
    float a0 = 0.f, a1 = 0.f, a2 = 0.f, a3 = 0.f;
    float a4 = 0.f, a5 = 0.f, a6 = 0.f, a7 = 0.f;
#pragma unroll 4
    for (int k = 0; k < 384; k += 8) {
        a0 = fmaf(avp[k + 0], Wp[(size_t)(k + 0) * 768], a0);
        a1 = fmaf(avp[k + 1], Wp[(size_t)(k + 1) * 768], a1);
        a2 = fmaf(avp[k + 2], Wp[(size_t)(k + 2) * 768], a2);
        a3 = fmaf(avp[k + 3], Wp[(size_t)(k + 3) * 768], a3);
        a4 = fmaf(avp[k + 4], Wp[(size_t)(k + 4) * 768], a4);
        a5 = fmaf(avp[k + 5], Wp[(size_t)(k + 5) * 768], a5);
        a6 = fmaf(avp[k + 6], Wp[(size_t)(k + 6) * 768], a6);
        a7 = fmaf(avp[k + 7], Wp[(size_t)(k + 7) * 768], a7);
    }
    psum[seg][jl] = ((a0 + a1) + (a2 + a3)) + ((a4 + a5) + (a6 + a7));
    __syncthreads();

    if (threadIdx.x < 128)
        av[threadIdx.x] = psum[0][threadIdx.x] + psum[1][threadIdx.x]
                        + bts[j0 + threadIdx.x];
    __syncthreads();
    if (threadIdx.x < 64) {
        const int e = (j0 >> 1) + threadIdx.x;
        float x0 = av[2 * threadIdx.x], x1 = av[2 * threadIdx.x + 1];
        float m = fmaxf(x0, x1);
        float e0 = __expf(x0 - m), e1 = __expf(x1 - m);
        float inv = 1.f / (e0 + e1);
        gate[(size_t)b * 768 + e] = e0 * inv;
        gate[(size_t)b * 768 + 384 + e] = e1 * inv;
    }
}

// ---------------------------------------------------------------------------
// xg = bf16(xcat * gate[b]), 8 elems/thread
// ---------------------------------------------------------------------------
__global__ __launch_bounds__(256) void gate_mul(
    const ushort* __restrict__ xcat, const float* __restrict__ gate,
    ushort* __restrict__ xg)
{
    const int i = blockIdx.x * 256 + threadIdx.x;
    const int m = i / 96;
    const int k = (i % 96) * 8;
    const int b = m >> 9;
    uint4 u = ((const uint4*)xcat)[i];
    const float* g = gate + (size_t)b * 768 + k;
    float4 g0 = *(const float4*)g;
    float4 g1 = *(const float4*)(g + 4);
    uint4 o;
    o.x = pk2(lo2f(u.x) * g0.x, hi2f(u.x) * g0.y);
    o.y = pk2(lo2f(u.y) * g0.z, hi2f(u.y) * g0.w);
    o.z = pk2(lo2f(u.z) * g1.x, hi2f(u.z) * g1.y);
    o.w = pk2(lo2f(u.w) * g1.z, hi2f(u.w) * g1.w);
    ((uint4*)xg)[i] = o;
}

// ---------------------------------------------------------------------------
extern "C" void kernel_launch(void* const* d_in, const int* in_sizes, int n_in,
                              void* d_out, int out_size, void* d_ws, size_t ws_size,
                              hipStream_t stream)
{
    const float* x      = (const float*)d_in[0];
    const float* Wqkv_t = (const float*)d_in[1];
    const float* bqkv_t = (const float*)d_in[2];
    const float* Wqkv_s = (const float*)d_in[3];
    const float* bqkv_s = (const float*)d_in[4];
    const float* Wts    = (const float*)d_in[5];
    const float* bts    = (const float*)d_in[6];
    const float* Wfc_t  = (const float*)d_in[7];
    const float* bfc_t  = (const float*)d_in[8];
    const float* Wfc_s  = (const float*)d_in[9];
    const float* bfc_s  = (const float*)d_in[10];
    float* out = (float*)d_out;

    char* w = (char*)d_ws;
    ushort* qkv2   = (ushort*)(w);                 // 16384*2304 bf16 = 75,497,472 B
    ushort* xg     = qkv2;                         // reuse (dead after attn)
    ushort* xcat   = (ushort*)(w + 75497472);      // 16384*768 bf16  = 25,165,824 B
    ushort* xb     = (ushort*)(w + 100663296);     // 16384*768 bf16  = 25,165,824 B
    ushort* wbuf   = (ushort*)(w + 125829120);     // 2304*768 bf16   =  3,538,944 B
    ushort* wbuf2  = (ushort*)(w + 129368064);     // 768*768 bf16    =  1,179,648 B
    float*  partial= (float*)(w + 130547712);      // 32*8*768 f32    =    786,432 B
    float*  gate   = (float*)(w + 131334144);      // 32*768 f32      =     98,304 B
    float*  bias2  = (float*)(w + 131432448);      // 2304 f32

    const dim3 blk256(256);

    // prep: x -> bf16; merged QKV weights wbuf[2304][768]; bias concat
    convert_bf16<<<dim3(6144), blk256, 0, stream>>>(x, xb);
    concat_bias<<<dim3(9), blk256, 0, stream>>>(bqkv_t, bqkv_s, bias2);
    transpose_w<<<dim3(24, 36), blk256, 0, stream>>>(Wqkv_t, wbuf, 768, 1152, 768, 0, 0);
    transpose_w<<<dim3(24, 36), blk256, 0, stream>>>(Wqkv_s, wbuf, 768, 1152, 768, 0, 1152);

    // merged QKV GEMM: [16384 x 2304] = xb @ wbuf^T + bias2
    gemm128s<1, 1><<<dim3(128, 18), blk256, 0, stream>>>(
        xb, wbuf, bias2, nullptr, qkv2, 16384, 2304, 768);

    attn_temporal<<<dim3(1024), blk256, 0, stream>>>(qkv2, xcat);
    attn_spatial<<<dim3(16384), dim3(192), 0, stream>>>(qkv2, xcat);

    // gating
    colsum<<<dim3(32, 3, 8), blk256, 0, stream>>>(xcat, partial);
    alpha_gate<<<dim3(32, 6), blk256, 0, stream>>>(partial, Wts, bts, gate);
    gate_mul<<<dim3(6144), blk256, 0, stream>>>(xcat, gate, xg);

    // final GEMM: wbuf2 = [Wfc_t; Wfc_s]^T -> [768 n][768 k]
    transpose_w<<<dim3(12, 24), blk256, 0, stream>>>(Wfc_t, wbuf2, 384, 768, 768, 0, 0);
    transpose_w<<<dim3(12, 24), blk256, 0, stream>>>(Wfc_s, wbuf2, 384, 768, 768, 384, 0);
    gemm128s<0, 2><<<dim3(128, 6), blk256, 0, stream>>>(
        xg, wbuf2, bfc_t, bfc_s, out, 16384, 768, 768);
}

// Round 14
// 190.433 us; speedup vs baseline: 1.3268x; 1.3257x over previous
//
#include <hip/hip_runtime.h>
#include <hip/hip_bf16.h>

// B=32, N=512, H=8, DH=48, E=384, IN=768, R=16384
// Merged QKV: qkv2[16384][2304] = [qkv_t (1152) | qkv_s (1152)] bf16

typedef __attribute__((ext_vector_type(8))) short s16x8;
typedef __attribute__((ext_vector_type(4))) float f32x4;

__device__ __forceinline__ float lo2f(uint u) { return __uint_as_float(u << 16); }
__device__ __forceinline__ float hi2f(uint u) { return __uint_as_float(u & 0xffff0000u); }
__device__ __forceinline__ ushort f2bu(float f) {
    union { __hip_bfloat16 h; ushort u; } c; c.h = __float2bfloat16(f); return c.u;
}
__device__ __forceinline__ uint pk2(float a, float b) {
    return (uint)f2bu(a) | ((uint)f2bu(b) << 16);
}
__device__ __forceinline__ void gload16(const void* g, void* l) {
    __builtin_amdgcn_global_load_lds((const __attribute__((address_space(1))) void*)g,
                                     (__attribute__((address_space(3))) void*)l, 16, 0, 0);
}

// ---------------------------------------------------------------------------
// Merged prep kernel: all independent pre-GEMM work in ONE launch so the
// sub-tasks run concurrently across CUs instead of serializing on the stream.
//   blocks [0, 6144):        x fp32 -> xb bf16 (8 elems/thread)
//   blocks [6144, 6153):     bias2 = concat(bqkv_t, bqkv_s)
//   blocks [6153, 7017):     Wqkv_t -> wbuf rows [0,1152)     (transpose)
//   blocks [7017, 7881):     Wqkv_s -> wbuf rows [1152,2304)  (transpose)
//   blocks [7881, 8169):     Wfc_t  -> wbuf2 k [0,384)        (transpose)
//   blocks [8169, 8457):     Wfc_s  -> wbuf2 k [384,768)      (transpose)
// ---------------------------------------------------------------------------
__device__ __forceinline__ void transpose_blk(
    const float* __restrict__ W, ushort* __restrict__ Bt,
    int task, int KT, int N, int Kt, int koff, int noff, float (*t)[33])
{
    const int k0 = (task % KT) * 32;
    const int n0 = (task / KT) * 32;
    const int r = threadIdx.x >> 3, cq = threadIdx.x & 7;
    float4 v = *(const float4*)(W + (size_t)(k0 + r) * N + n0 + cq * 4);
    t[r][cq * 4 + 0] = v.x; t[r][cq * 4 + 1] = v.y;
    t[r][cq * 4 + 2] = v.z; t[r][cq * 4 + 3] = v.w;
    __syncthreads();
    ushort4 o;
    o.x = f2bu(t[cq * 4 + 0][r]); o.y = f2bu(t[cq * 4 + 1][r]);
    o.z = f2bu(t[cq * 4 + 2][r]); o.w = f2bu(t[cq * 4 + 3][r]);
    *(ushort4*)(Bt + (size_t)(noff + n0 + r) * Kt + koff + k0 + cq * 4) = o;
}

__global__ __launch_bounds__(256) void prep(
    const float* __restrict__ x, ushort* __restrict__ xb,
    const float* __restrict__ bqkv_t, const float* __restrict__ bqkv_s,
    float* __restrict__ bias2,
    const float* __restrict__ Wqkv_t, const float* __restrict__ Wqkv_s,
    ushort* __restrict__ wbuf,
    const float* __restrict__ Wfc_t, const float* __restrict__ Wfc_s,
    ushort* __restrict__ wbuf2)
{
    __shared__ float t[32][33];
    const int bid = blockIdx.x;
    if (bid < 6144) {
        const int i = bid * 256 + threadIdx.x;
        const float4* p = (const float4*)x + (size_t)i * 2;
        float4 a = p[0], b = p[1];
        uint4 o;
        o.x = pk2(a.x, a.y); o.y = pk2(a.z, a.w);
        o.z = pk2(b.x, b.y); o.w = pk2(b.z, b.w);
        ((uint4*)xb)[i] = o;
    } else if (bid < 6153) {
        const int i = (bid - 6144) * 256 + threadIdx.x;
        bias2[i] = (i < 1152) ? bqkv_t[i] : bqkv_s[i - 1152];
    } else if (bid < 7017) {
        transpose_blk(Wqkv_t, wbuf, bid - 6153, 24, 1152, 768, 0, 0, t);
    } else if (bid < 7881) {
        transpose_blk(Wqkv_s, wbuf, bid - 7017, 24, 1152, 768, 0, 1152, t);
    } else if (bid < 8169) {
        transpose_blk(Wfc_t, wbuf2, bid - 7881, 12, 768, 768, 0, 0, t);
    } else {
        transpose_blk(Wfc_s, wbuf2, bid - 8169, 12, 768, 768, 384, 0, t);
    }
}

// ---------------------------------------------------------------------------
// 128x128 MFMA GEMM (r8-proven, best measured: 784 TF), BK=64, 256 thr =
// 4 waves (2x2), counted-vmcnt pipeline: tile t+1's 8 global_load_lds stay
// in flight across BOTH barriers (s_waitcnt vmcnt(8), never 0 in-loop).
// 2 LDS bufs x 32 KB = 64 KB -> 2 blocks/CU. 16B-chunk XOR swizzle via
// pre-swizzled global source (dest linear). C = A @ Bt^T + bias.
// ---------------------------------------------------------------------------
template<int OUTBF16, int NBIAS>
__global__ __launch_bounds__(256, 2) void gemm128p(
    const ushort* __restrict__ A, const ushort* __restrict__ Bt,
    const float* __restrict__ bias0, const float* __restrict__ bias1,
    void* __restrict__ Cout, int M, int N, int K)
{
    __shared__ ushort smem[32768];   // buf0: A[0,8K) B[8K,16K); buf1: +16K
    const int tid = threadIdx.x;
    const int m0 = blockIdx.x * 128;
    const int n0 = blockIdx.y * 128;
    const int lane = tid & 63;
    const int wr = tid >> 7;
    const int wc = (tid >> 6) & 1;
    const int lr = lane & 15;
    const int g = lane >> 4;

    f32x4 acc[4][4];
#pragma unroll
    for (int i = 0; i < 4; ++i)
#pragma unroll
        for (int j = 0; j < 4; ++j) acc[i][j] = (f32x4){0.f, 0.f, 0.f, 0.f};

    int rowT[4], kqs[4];
#pragma unroll
    for (int i = 0; i < 4; ++i) {
        const int task = tid + 256 * i;
        rowT[i] = task >> 3;
        kqs[i] = (task & 7) ^ (rowT[i] & 7);
    }

    auto stage = [&](int buf, int k0) {
        ushort* dA = &smem[buf * 16384];
        ushort* dB = &smem[buf * 16384 + 8192];
#pragma unroll
        for (int i = 0; i < 4; ++i) {
            gload16(A + (size_t)(m0 + rowT[i]) * K + k0 + (kqs[i] << 3),
                    dA + (tid + 256 * i) * 8);
            gload16(Bt + (size_t)(n0 + rowT[i]) * K + k0 + (kqs[i] << 3),
                    dB + (tid + 256 * i) * 8);
        }
    };

    stage(0, 0);                      // 8 loads in flight
    const int nt = K >> 6;
    for (int t = 0; t < nt; ++t) {
        const int cur = t & 1;
        if (t + 1 < nt) {
            stage(cur ^ 1, (t + 1) << 6);                    // +8 (16 total)
            asm volatile("s_waitcnt vmcnt(8)" ::: "memory");  // tile t landed;
        } else {                                              // t+1 in flight
            asm volatile("s_waitcnt vmcnt(0)" ::: "memory");
        }
        __builtin_amdgcn_sched_barrier(0);
        __builtin_amdgcn_s_barrier();
        __builtin_amdgcn_sched_barrier(0);

        const ushort* As = &smem[cur * 16384];
        const ushort* Bs = &smem[cur * 16384 + 8192];
#pragma unroll
        for (int half = 0; half < 2; ++half) {
            s16x8 af[4], bfv[4];
#pragma unroll
            for (int i = 0; i < 4; ++i) {
                const int row = wr * 64 + 16 * i + lr;
                af[i] = *(const s16x8*)&As[row * 64
                         + (((4 * half + g) ^ (row & 7)) << 3)];
            }
#pragma unroll
            for (int j = 0; j < 4; ++j) {
                const int row = wc * 64 + 16 * j + lr;
                bfv[j] = *(const s16x8*)&Bs[row * 64
                          + (((4 * half + g) ^ (row & 7)) << 3)];
            }
#pragma unroll
            for (int i = 0; i < 4; ++i)
#pragma unroll
                for (int j = 0; j < 4; ++j)
                    acc[i][j] = __builtin_amdgcn_mfma_f32_16x16x32_bf16(
                        af[i], bfv[j], acc[i][j], 0, 0, 0);
        }
        __builtin_amdgcn_sched_barrier(0);
        __builtin_amdgcn_s_barrier();   // WAR: next iter overwrites buf cur
    }

    const int c0 = n0 + wc * 64 + lr;
    float bsum[4];
#pragma unroll
    for (int j = 0; j < 4; ++j) {
        bsum[j] = bias0[c0 + 16 * j];
        if (NBIAS == 2) bsum[j] += bias1[c0 + 16 * j];
    }
    const int r0 = m0 + wr * 64 + g * 4;
#pragma unroll
    for (int i = 0; i < 4; ++i) {
        const int row = r0 + 16 * i;
#pragma unroll
        for (int j = 0; j < 4; ++j) {
            const int col = c0 + 16 * j;
#pragma unroll
            for (int v = 0; v < 4; ++v) {
                const float val = acc[i][j][v] + bsum[j];
                if (OUTBF16)
                    ((ushort*)Cout)[(size_t)(row + v) * N + col] = f2bu(val);
                else
                    ((float*)Cout)[(size_t)(row + v) * N + col] = val;
            }
        }
    }
}

// ---------------------------------------------------------------------------
// Temporal flash attention, MFMA. Grid 1024 (XCD-remapped), 256 thr = 4 waves.
// qkv2 row stride 2304 ushorts; temporal qkv at cols [0,1152).
// ---------------------------------------------------------------------------
__global__ __launch_bounds__(256, 4) void attn_temporal(
    const ushort* __restrict__ qkv, ushort* __restrict__ xcat)
{
    const int wg = blockIdx.x;
    const int cx = wg & 7, rx = wg >> 3;
    const int id = ((rx >> 2) << 5) + 4 * cx + (rx & 3);
    const int qt = id & 3;
    const int h = (id >> 2) & 7;
    const int b = id >> 5;

    const int tid = threadIdx.x;
    const int w = tid >> 6;
    const int lane = tid & 63;
    const int lr = lane & 15;
    const int g = lane >> 4;

    __shared__ ushort Ks[64 * 64];      // [kv][d], cols 48..63 zero
    __shared__ ushort Vt[48 * 64];      // [d][kv]
    __shared__ ushort Pl[4][32 * 72];
    uint* KsU = (uint*)Ks;
    uint* VtU = (uint*)Vt;

    ((uint4*)Ks)[tid] = make_uint4(0u, 0u, 0u, 0u);
    ((uint4*)Ks)[256 + tid] = make_uint4(0u, 0u, 0u, 0u);
    __syncthreads();

    const uint* qkvu = (const uint*)qkv;
    const int qrow0 = qt * 128 + w * 32;

    s16x8 qf[2][2];
#pragma unroll
    for (int n = 0; n < 2; ++n) {
        const size_t rb = (size_t)(b * 512 + qrow0 + 16 * n + lr) * 2304 + h * 48 + 8 * g;
        qf[n][0] = *(const s16x8*)(qkv + rb);
        qf[n][1] = (g < 2) ? *(const s16x8*)(qkv + rb + 32)
                           : (s16x8){0, 0, 0, 0, 0, 0, 0, 0};
    }

    int p_[3], du_[3];
#pragma unroll
    for (int i = 0; i < 3; ++i) {
        const int idx = tid + 256 * i;
        p_[i] = idx / 24;
        du_[i] = idx % 24;
    }
    uint rk[3][2], rv[3][2];

    auto stage_load = [&](int kv0) {
#pragma unroll
        for (int i = 0; i < 3; ++i) {
            const uint* s0 = qkvu + (size_t)(b * 512 + kv0 + 2 * p_[i]) * 1152
                                  + 192 + h * 24 + du_[i];
            rk[i][0] = s0[0];    rk[i][1] = s0[1152];
            rv[i][0] = s0[192];  rv[i][1] = s0[192 + 1152];
        }
    };
    auto stage_write = [&]() {
#pragma unroll
        for (int i = 0; i < 3; ++i) {
            const int p = p_[i], du = du_[i];
            KsU[(2 * p) * 32 + ((((du >> 2) ^ ((2 * p) & 7)) << 2) | (du & 3))] = rk[i][0];
            KsU[(2 * p + 1) * 32 + ((((du >> 2) ^ ((2 * p + 1) & 7)) << 2) | (du & 3))] = rk[i][1];
            const uint w0 = (rv[i][0] & 0xffffu) | (rv[i][1] << 16);
            const uint w1 = (rv[i][0] >> 16) | (rv[i][1] & 0xffff0000u);
            const int vb = (((p >> 2) ^ (du & 7)) << 2) | (p & 3);
            VtU[(2 * du) * 32 + vb] = w0;
            VtU[(2 * du + 1) * 32 + vb] = w1;
        }
    };

    f32x4 o[2][3];
#pragma unroll
    for (int mq = 0; mq < 2; ++mq)
#pragma unroll
        for (int nd = 0; nd < 3; ++nd) o[mq][nd] = (f32x4){0.f, 0.f, 0.f, 0.f};
    float mrun[2] = {-3.0e38f, -3.0e38f};
    float lsum[2] = {0.f, 0.f};
    float corrv[2];
    const float scale = 0.14433756729740643f; // 1/sqrt(48)

    stage_load(0);
    stage_write();
    __syncthreads();

    for (int t = 0; t < 8; ++t) {
        if (t < 7) stage_load((t + 1) * 64);

        f32x4 sa[4][2];
#pragma unroll
        for (int m = 0; m < 4; ++m)
#pragma unroll
            for (int n = 0; n < 2; ++n) sa[m][n] = (f32x4){0.f, 0.f, 0.f, 0.f};
        __builtin_amdgcn_s_setprio(1);
#pragma unroll
        for (int ks = 0; ks < 2; ++ks)
#pragma unroll
            for (int m = 0; m < 4; ++m) {
                s16x8 kf = *(const s16x8*)&Ks[(16 * m + lr) * 64
                                              + (((g + 4 * ks) ^ (lr & 7)) << 3)];
#pragma unroll
                for (int n = 0; n < 2; ++n)
                    sa[m][n] = __builtin_amdgcn_mfma_f32_16x16x32_bf16(
                        kf, qf[n][ks], sa[m][n], 0, 0, 0);
            }
        __builtin_amdgcn_s_setprio(0);

#pragma unroll
        for (int n = 0; n < 2; ++n) {
            float tmax = -3.0e38f;
#pragma unroll
            for (int m = 0; m < 4; ++m)
#pragma unroll
                for (int v = 0; v < 4; ++v) tmax = fmaxf(tmax, sa[m][n][v]);
            tmax = fmaxf(tmax, __shfl_xor(tmax, 16));
            tmax = fmaxf(tmax, __shfl_xor(tmax, 32));
            float mnew = fmaxf(mrun[n], tmax * scale);
            float corr = __expf(mrun[n] - mnew);
            mrun[n] = mnew;
            float psum = 0.f;
#pragma unroll
            for (int m = 0; m < 4; ++m) {
                float p0 = __expf(fmaf(sa[m][n][0], scale, -mnew));
                float p1 = __expf(fmaf(sa[m][n][1], scale, -mnew));
                float p2 = __expf(fmaf(sa[m][n][2], scale, -mnew));
                float p3 = __expf(fmaf(sa[m][n][3], scale, -mnew));
                psum += (p0 + p1) + (p2 + p3);
                const int base = (16 * n + lr) * 72 + 16 * m + 4 * g;
                *(uint*)&Pl[w][base] = pk2(p0, p1);
                *(uint*)&Pl[w][base + 2] = pk2(p2, p3);
            }
            psum += __shfl_xor(psum, 16);
            psum += __shfl_xor(psum, 32);
            lsum[n] = lsum[n] * corr + psum;
            corrv[n] = corr;
        }

#pragma unroll
        for (int mq = 0; mq < 2; ++mq)
#pragma unroll
            for (int nd = 0; nd < 3; ++nd)
#pragma unroll
                for (int v = 0; v < 4; ++v) o[mq][nd][v] *= corrv[mq];

        __builtin_amdgcn_s_setprio(1);
#pragma unroll
        for (int ks = 0; ks < 2; ++ks) {
            s16x8 vf[3];
#pragma unroll
            for (int nd = 0; nd < 3; ++nd)
                vf[nd] = *(const s16x8*)&Vt[(16 * nd + lr) * 64
                                            + (((g + 4 * ks) ^ (lr >> 1)) << 3)];
#pragma unroll
            for (int mq = 0; mq < 2; ++mq) {
                s16x8 pf = *(const s16x8*)&Pl[w][(16 * mq + lr) * 72 + 8 * g + 32 * ks];
#pragma unroll
                for (int nd = 0; nd < 3; ++nd)
                    o[mq][nd] = __builtin_amdgcn_mfma_f32_16x16x32_bf16(
                        vf[nd], pf, o[mq][nd], 0, 0, 0);
            }
        }
        __builtin_amdgcn_s_setprio(0);
        __syncthreads();
        if (t < 7) stage_write();
        __syncthreads();
    }

#pragma unroll
    for (int mq = 0; mq < 2; ++mq) {
        const float li = 1.f / lsum[mq];
        const int qrow = qrow0 + 16 * mq + lr;
        ushort* dst = xcat + (size_t)(b * 512 + qrow) * 768 + h * 48;
#pragma unroll
        for (int nd = 0; nd < 3; ++nd) {
            uint2 o2;
            o2.x = pk2(o[mq][nd][0] * li, o[mq][nd][1] * li);
            o2.y = pk2(o[mq][nd][2] * li, o[mq][nd][3] * li);
            *(uint2*)(dst + 16 * nd + 4 * g) = o2;
        }
    }
}

// ---------------------------------------------------------------------------
// Spatial attention (unscaled). One block per g. 192 thr = 8h x 24t.
// Spatial qkv at ushort cols [1152, 2304) of qkv2.
// ---------------------------------------------------------------------------
__global__ __launch_bounds__(192) void attn_spatial(
    const ushort* __restrict__ qkv, ushort* __restrict__ xcat)
{
    const int g = blockIdx.x;
    __shared__ float row[1152];
    const uint* qkvu = (const uint*)qkv;
#pragma unroll
    for (int i = 0; i < 3; ++i) {
        int idx = threadIdx.x + 192 * i;
        uint u = qkvu[(size_t)g * 1152 + 576 + idx];
        row[2 * idx] = lo2f(u); row[2 * idx + 1] = hi2f(u);
    }
    __syncthreads();

    const int h = threadIdx.x / 24;
    const int t = threadIdx.x % 24;
    const float* q = &row[h * 48];
    const float* k = &row[384 + h * 48];
    const float* v = &row[768 + h * 48];
    const float q0 = q[t], q1 = q[24 + t];

    float s[24];
    float mx = -3.0e38f;
#pragma unroll
    for (int u = 0; u < 24; ++u) {
        s[u] = q0 * k[u] + q1 * k[24 + u];
        mx = fmaxf(mx, s[u]);
    }
    float l = 0.f;
#pragma unroll
    for (int u = 0; u < 24; ++u) { s[u] = __expf(s[u] - mx); l += s[u]; }
    const float inv = 1.f / l;
    float o0 = 0.f, o1 = 0.f;
#pragma unroll
    for (int u = 0; u < 24; ++u) {
        o0 = fmaf(s[u], v[u], o0);
        o1 = fmaf(s[u], v[24 + u], o1);
    }
    ushort* dst = xcat + (size_t)g * 768 + 384 + h * 48;
    dst[t] = f2bu(o0 * inv);
    dst[24 + t] = f2bu(o1 * inv);
}

// ---------------------------------------------------------------------------
// Column partial sums (bf16 in, fp32 out). grid (32,3,8).
// ---------------------------------------------------------------------------
__global__ __launch_bounds__(256) void colsum(
    const ushort* __restrict__ xcat, float* __restrict__ partial)
{
    const int b = blockIdx.x, ch = blockIdx.y, part = blockIdx.z;
    const int e = ch * 256 + threadIdx.x;
    const int n0 = part * 64;
    float s = 0.f;
    for (int n = 0; n < 64; ++n)
        s += __uint_as_float((uint)xcat[((size_t)(b * 512 + n0 + n)) * 768 + e] << 16);
    partial[((size_t)(b * 8 + part)) * 768 + e] = s;
}

// ---------------------------------------------------------------------------
// Gating, parallel. grid (32 b, 6 j-tiles of 128), 256 thr.
// ---------------------------------------------------------------------------
__global__ __launch_bounds__(256) void alpha_gate(
    const float* __restrict__ partial, const float* __restrict__ Wts,
    const float* __restrict__ bts, float* __restrict__ gate)
{
    const int b = blockIdx.x;
    const int j0 = blockIdx.y * 128;
    __shared__ float av[768];
    __shared__ float psum[2][128];

    for (int i = threadIdx.x; i < 768; i += 256) {
        float s = 0.f;
#pragma unroll
        for (int p = 0; p < 8; ++p)
            s += partial[((size_t)(b * 8 + p)) * 768 + i];
        av[i] = s * (1.0f / 512.0f);
    }
    __syncthreads();

    const int jl = threadIdx.x & 127;
    const int seg = threadIdx.x >> 7;
    const int j = j0 + jl;
    const float* Wp = Wts + (size_t)(seg * 384) * 768 + j;
    const float* avp = av + seg * 384;
    float a0 = 0.f, a1 = 0.f, a2 = 0.f, a3 = 0.f;
    float a4 = 0.f, a5 = 0.f, a6 = 0.f, a7 = 0.f;
#pragma unroll 4
    for (int k = 0; k < 384; k += 8) {
        a0 = fmaf(avp[k + 0], Wp[(size_t)(k + 0) * 768], a0);
        a1 = fmaf(avp[k + 1], Wp[(size_t)(k + 1) * 768], a1);
        a2 = fmaf(avp[k + 2], Wp[(size_t)(k + 2) * 768], a2);
        a3 = fmaf(avp[k + 3], Wp[(size_t)(k + 3) * 768], a3);
        a4 = fmaf(avp[k + 4], Wp[(size_t)(k + 4) * 768], a4);
        a5 = fmaf(avp[k + 5], Wp[(size_t)(k + 5) * 768], a5);
        a6 = fmaf(avp[k + 6], Wp[(size_t)(k + 6) * 768], a6);
        a7 = fmaf(avp[k + 7], Wp[(size_t)(k + 7) * 768], a7);
    }
    psum[seg][jl] = ((a0 + a1) + (a2 + a3)) + ((a4 + a5) + (a6 + a7));
    __syncthreads();

    if (threadIdx.x < 128)
        av[threadIdx.x] = psum[0][threadIdx.x] + psum[1][threadIdx.x]
                        + bts[j0 + threadIdx.x];
    __syncthreads();
    if (threadIdx.x < 64) {
        const int e = (j0 >> 1) + threadIdx.x;
        float x0 = av[2 * threadIdx.x], x1 = av[2 * threadIdx.x + 1];
        float m = fmaxf(x0, x1);
        float e0 = __expf(x0 - m), e1 = __expf(x1 - m);
        float inv = 1.f / (e0 + e1);
        gate[(size_t)b * 768 + e] = e0 * inv;
        gate[(size_t)b * 768 + 384 + e] = e1 * inv;
    }
}

// ---------------------------------------------------------------------------
// xg = bf16(xcat * gate[b]), 8 elems/thread
// ---------------------------------------------------------------------------
__global__ __launch_bounds__(256) void gate_mul(
    const ushort* __restrict__ xcat, const float* __restrict__ gate,
    ushort* __restrict__ xg)
{
    const int i = blockIdx.x * 256 + threadIdx.x;
    const int m = i / 96;
    const int k = (i % 96) * 8;
    const int b = m >> 9;
    uint4 u = ((const uint4*)xcat)[i];
    const float* g = gate + (size_t)b * 768 + k;
    float4 g0 = *(const float4*)g;
    float4 g1 = *(const float4*)(g + 4);
    uint4 o;
    o.x = pk2(lo2f(u.x) * g0.x, hi2f(u.x) * g0.y);
    o.y = pk2(lo2f(u.y) * g0.z, hi2f(u.y) * g0.w);
    o.z = pk2(lo2f(u.z) * g1.x, hi2f(u.z) * g1.y);
    o.w = pk2(lo2f(u.w) * g1.z, hi2f(u.w) * g1.w);
    ((uint4*)xg)[i] = o;
}

// ---------------------------------------------------------------------------
extern "C" void kernel_launch(void* const* d_in, const int* in_sizes, int n_in,
                              void* d_out, int out_size, void* d_ws, size_t ws_size,
                              hipStream_t stream)
{
    const float* x      = (const float*)d_in[0];
    const float* Wqkv_t = (const float*)d_in[1];
    const float* bqkv_t = (const float*)d_in[2];
    const float* Wqkv_s = (const float*)d_in[3];
    const float* bqkv_s = (const float*)d_in[4];
    const float* Wts    = (const float*)d_in[5];
    const float* bts    = (const float*)d_in[6];
    const float* Wfc_t  = (const float*)d_in[7];
    const float* bfc_t  = (const float*)d_in[8];
    const float* Wfc_s  = (const float*)d_in[9];
    const float* bfc_s  = (const float*)d_in[10];
    float* out = (float*)d_out;

    char* w = (char*)d_ws;
    ushort* qkv2   = (ushort*)(w);                 // 16384*2304 bf16 = 75,497,472 B
    ushort* xg     = qkv2;                         // reuse (dead after attn)
    ushort* xcat   = (ushort*)(w + 75497472);      // 16384*768 bf16  = 25,165,824 B
    ushort* xb     = (ushort*)(w + 100663296);     // 16384*768 bf16  = 25,165,824 B
    ushort* wbuf   = (ushort*)(w + 125829120);     // 2304*768 bf16   =  3,538,944 B
    ushort* wbuf2  = (ushort*)(w + 129368064);     // 768*768 bf16    =  1,179,648 B
    float*  partial= (float*)(w + 130547712);      // 32*8*768 f32    =    786,432 B
    float*  gate   = (float*)(w + 131334144);      // 32*768 f32      =     98,304 B
    float*  bias2  = (float*)(w + 131432448);      // 2304 f32

    const dim3 blk256(256);

    // one merged prep launch (convert + bias concat + 4 weight transposes)
    prep<<<dim3(8457), blk256, 0, stream>>>(
        x, xb, bqkv_t, bqkv_s, bias2, Wqkv_t, Wqkv_s, wbuf, Wfc_t, Wfc_s, wbuf2);

    // merged QKV GEMM: [16384 x 2304] = xb @ wbuf^T + bias2
    gemm128p<1, 1><<<dim3(128, 18), blk256, 0, stream>>>(
        xb, wbuf, bias2, nullptr, qkv2, 16384, 2304, 768);

    attn_temporal<<<dim3(1024), blk256, 0, stream>>>(qkv2, xcat);
    attn_spatial<<<dim3(16384), dim3(192), 0, stream>>>(qkv2, xcat);

    // gating
    colsum<<<dim3(32, 3, 8), blk256, 0, stream>>>(xcat, partial);
    alpha_gate<<<dim3(32, 6), blk256, 0, stream>>>(partial, Wts, bts, gate);
    gate_mul<<<dim3(6144), blk256, 0, stream>>>(xcat, gate, xg);

    // final GEMM
    gemm128p<0, 2><<<dim3(128, 6), blk256, 0, stream>>>(
        xg, wbuf2, bfc_t, bfc_s, out, 16384, 768, 768);
}

// Round 15
// 190.222 us; speedup vs baseline: 1.3283x; 1.0011x over previous
//
#include <hip/hip_runtime.h>
#include <hip/hip_bf16.h>

// B=32, N=512, H=8, DH=48, E=384, IN=768, R=16384
// Merged QKV: qkv2[16384][2304] = [qkv_t (1152) | qkv_s (1152)] bf16

typedef __attribute__((ext_vector_type(8))) short s16x8;
typedef __attribute__((ext_vector_type(4))) float f32x4;

__device__ __forceinline__ float lo2f(uint u) { return __uint_as_float(u << 16); }
__device__ __forceinline__ float hi2f(uint u) { return __uint_as_float(u & 0xffff0000u); }
__device__ __forceinline__ ushort f2bu(float f) {
    union { __hip_bfloat16 h; ushort u; } c; c.h = __float2bfloat16(f); return c.u;
}
__device__ __forceinline__ uint pk2(float a, float b) {
    return (uint)f2bu(a) | ((uint)f2bu(b) << 16);
}
__device__ __forceinline__ void gload16(const void* g, void* l) {
    __builtin_amdgcn_global_load_lds((const __attribute__((address_space(1))) void*)g,
                                     (__attribute__((address_space(3))) void*)l, 16, 0, 0);
}

// ---------------------------------------------------------------------------
// Merged prep kernel (r14-proven): convert + bias concat + 4 transposes.
// ---------------------------------------------------------------------------
__device__ __forceinline__ void transpose_blk(
    const float* __restrict__ W, ushort* __restrict__ Bt,
    int task, int KT, int N, int Kt, int koff, int noff, float (*t)[33])
{
    const int k0 = (task % KT) * 32;
    const int n0 = (task / KT) * 32;
    const int r = threadIdx.x >> 3, cq = threadIdx.x & 7;
    float4 v = *(const float4*)(W + (size_t)(k0 + r) * N + n0 + cq * 4);
    t[r][cq * 4 + 0] = v.x; t[r][cq * 4 + 1] = v.y;
    t[r][cq * 4 + 2] = v.z; t[r][cq * 4 + 3] = v.w;
    __syncthreads();
    ushort4 o;
    o.x = f2bu(t[cq * 4 + 0][r]); o.y = f2bu(t[cq * 4 + 1][r]);
    o.z = f2bu(t[cq * 4 + 2][r]); o.w = f2bu(t[cq * 4 + 3][r]);
    *(ushort4*)(Bt + (size_t)(noff + n0 + r) * Kt + koff + k0 + cq * 4) = o;
}

__global__ __launch_bounds__(256) void prep(
    const float* __restrict__ x, ushort* __restrict__ xb,
    const float* __restrict__ bqkv_t, const float* __restrict__ bqkv_s,
    float* __restrict__ bias2,
    const float* __restrict__ Wqkv_t, const float* __restrict__ Wqkv_s,
    ushort* __restrict__ wbuf,
    const float* __restrict__ Wfc_t, const float* __restrict__ Wfc_s,
    ushort* __restrict__ wbuf2)
{
    __shared__ float t[32][33];
    const int bid = blockIdx.x;
    if (bid < 6144) {
        const int i = bid * 256 + threadIdx.x;
        const float4* p = (const float4*)x + (size_t)i * 2;
        float4 a = p[0], b = p[1];
        uint4 o;
        o.x = pk2(a.x, a.y); o.y = pk2(a.z, a.w);
        o.z = pk2(b.x, b.y); o.w = pk2(b.z, b.w);
        ((uint4*)xb)[i] = o;
    } else if (bid < 6153) {
        const int i = (bid - 6144) * 256 + threadIdx.x;
        bias2[i] = (i < 1152) ? bqkv_t[i] : bqkv_s[i - 1152];
    } else if (bid < 7017) {
        transpose_blk(Wqkv_t, wbuf, bid - 6153, 24, 1152, 768, 0, 0, t);
    } else if (bid < 7881) {
        transpose_blk(Wqkv_s, wbuf, bid - 7017, 24, 1152, 768, 0, 1152, t);
    } else if (bid < 8169) {
        transpose_blk(Wfc_t, wbuf2, bid - 7881, 12, 768, 768, 0, 0, t);
    } else {
        transpose_blk(Wfc_s, wbuf2, bid - 8169, 12, 768, 768, 384, 0, t);
    }
}

// ---------------------------------------------------------------------------
// 128x128 MFMA GEMM (r8-proven, 784 TF), BK=64, counted-vmcnt pipeline.
// ---------------------------------------------------------------------------
template<int OUTBF16, int NBIAS>
__global__ __launch_bounds__(256, 2) void gemm128p(
    const ushort* __restrict__ A, const ushort* __restrict__ Bt,
    const float* __restrict__ bias0, const float* __restrict__ bias1,
    void* __restrict__ Cout, int M, int N, int K)
{
    __shared__ ushort smem[32768];
    const int tid = threadIdx.x;
    const int m0 = blockIdx.x * 128;
    const int n0 = blockIdx.y * 128;
    const int lane = tid & 63;
    const int wr = tid >> 7;
    const int wc = (tid >> 6) & 1;
    const int lr = lane & 15;
    const int g = lane >> 4;

    f32x4 acc[4][4];
#pragma unroll
    for (int i = 0; i < 4; ++i)
#pragma unroll
        for (int j = 0; j < 4; ++j) acc[i][j] = (f32x4){0.f, 0.f, 0.f, 0.f};

    int rowT[4], kqs[4];
#pragma unroll
    for (int i = 0; i < 4; ++i) {
        const int task = tid + 256 * i;
        rowT[i] = task >> 3;
        kqs[i] = (task & 7) ^ (rowT[i] & 7);
    }

    auto stage = [&](int buf, int k0) {
        ushort* dA = &smem[buf * 16384];
        ushort* dB = &smem[buf * 16384 + 8192];
#pragma unroll
        for (int i = 0; i < 4; ++i) {
            gload16(A + (size_t)(m0 + rowT[i]) * K + k0 + (kqs[i] << 3),
                    dA + (tid + 256 * i) * 8);
            gload16(Bt + (size_t)(n0 + rowT[i]) * K + k0 + (kqs[i] << 3),
                    dB + (tid + 256 * i) * 8);
        }
    };

    stage(0, 0);
    const int nt = K >> 6;
    for (int t = 0; t < nt; ++t) {
        const int cur = t & 1;
        if (t + 1 < nt) {
            stage(cur ^ 1, (t + 1) << 6);
            asm volatile("s_waitcnt vmcnt(8)" ::: "memory");
        } else {
            asm volatile("s_waitcnt vmcnt(0)" ::: "memory");
        }
        __builtin_amdgcn_sched_barrier(0);
        __builtin_amdgcn_s_barrier();
        __builtin_amdgcn_sched_barrier(0);

        const ushort* As = &smem[cur * 16384];
        const ushort* Bs = &smem[cur * 16384 + 8192];
#pragma unroll
        for (int half = 0; half < 2; ++half) {
            s16x8 af[4], bfv[4];
#pragma unroll
            for (int i = 0; i < 4; ++i) {
                const int row = wr * 64 + 16 * i + lr;
                af[i] = *(const s16x8*)&As[row * 64
                         + (((4 * half + g) ^ (row & 7)) << 3)];
            }
#pragma unroll
            for (int j = 0; j < 4; ++j) {
                const int row = wc * 64 + 16 * j + lr;
                bfv[j] = *(const s16x8*)&Bs[row * 64
                          + (((4 * half + g) ^ (row & 7)) << 3)];
            }
#pragma unroll
            for (int i = 0; i < 4; ++i)
#pragma unroll
                for (int j = 0; j < 4; ++j)
                    acc[i][j] = __builtin_amdgcn_mfma_f32_16x16x32_bf16(
                        af[i], bfv[j], acc[i][j], 0, 0, 0);
        }
        __builtin_amdgcn_sched_barrier(0);
        __builtin_amdgcn_s_barrier();
    }

    const int c0 = n0 + wc * 64 + lr;
    float bsum[4];
#pragma unroll
    for (int j = 0; j < 4; ++j) {
        bsum[j] = bias0[c0 + 16 * j];
        if (NBIAS == 2) bsum[j] += bias1[c0 + 16 * j];
    }
    const int r0 = m0 + wr * 64 + g * 4;
#pragma unroll
    for (int i = 0; i < 4; ++i) {
        const int row = r0 + 16 * i;
#pragma unroll
        for (int j = 0; j < 4; ++j) {
            const int col = c0 + 16 * j;
#pragma unroll
            for (int v = 0; v < 4; ++v) {
                const float val = acc[i][j][v] + bsum[j];
                if (OUTBF16)
                    ((ushort*)Cout)[(size_t)(row + v) * N + col] = f2bu(val);
                else
                    ((float*)Cout)[(size_t)(row + v) * N + col] = val;
            }
        }
    }
}

// ---------------------------------------------------------------------------
// FUSED attention: blocks [0,1024) = temporal (XCD-remapped, 4 waves);
// blocks [1024, 17408) = spatial (one g per block, 192 of 256 thr active).
// Temporal adds T13 defer-max (wave-uniform rescale skip, THR=4).
// ---------------------------------------------------------------------------
__global__ __launch_bounds__(256, 4) void attn_fused(
    const ushort* __restrict__ qkv, ushort* __restrict__ xcat)
{
    __shared__ ushort Ks[64 * 64];      // [kv][d], cols 48..63 zero (temporal)
    __shared__ ushort Vt[48 * 64];      // [d][kv]
    __shared__ ushort Pl[4][32 * 72];
    const int tid = threadIdx.x;
    const uint* qkvu = (const uint*)qkv;

    if (blockIdx.x >= 1024) {
        // ================= spatial attention (unscaled logits) ==============
        const int g = blockIdx.x - 1024;
        float* row = (float*)Ks;        // 1152 floats = 4.6 KB, fits in Ks
        if (tid < 192) {
#pragma unroll
            for (int i = 0; i < 3; ++i) {
                int idx = tid + 192 * i;
                uint u = qkvu[(size_t)g * 1152 + 576 + idx];
                row[2 * idx] = lo2f(u); row[2 * idx + 1] = hi2f(u);
            }
        }
        __syncthreads();
        if (tid < 192) {
            const int h = tid / 24;
            const int t = tid % 24;
            const float* q = &row[h * 48];
            const float* k = &row[384 + h * 48];
            const float* v = &row[768 + h * 48];
            const float q0 = q[t], q1 = q[24 + t];
            float s[24];
            float mx = -3.0e38f;
#pragma unroll
            for (int u = 0; u < 24; ++u) {
                s[u] = q0 * k[u] + q1 * k[24 + u];
                mx = fmaxf(mx, s[u]);
            }
            float l = 0.f;
#pragma unroll
            for (int u = 0; u < 24; ++u) { s[u] = __expf(s[u] - mx); l += s[u]; }
            const float inv = 1.f / l;
            float o0 = 0.f, o1 = 0.f;
#pragma unroll
            for (int u = 0; u < 24; ++u) {
                o0 = fmaf(s[u], v[u], o0);
                o1 = fmaf(s[u], v[24 + u], o1);
            }
            ushort* dst = xcat + (size_t)g * 768 + 384 + h * 48;
            dst[t] = f2bu(o0 * inv);
            dst[24 + t] = f2bu(o1 * inv);
        }
        return;
    }

    // ==================== temporal flash attention ==========================
    const int wg = blockIdx.x;
    const int cx = wg & 7, rx = wg >> 3;
    const int id = ((rx >> 2) << 5) + 4 * cx + (rx & 3);
    const int qt = id & 3;
    const int h = (id >> 2) & 7;
    const int b = id >> 5;

    const int w = tid >> 6;
    const int lane = tid & 63;
    const int lr = lane & 15;
    const int g = lane >> 4;
    uint* KsU = (uint*)Ks;
    uint* VtU = (uint*)Vt;

    ((uint4*)Ks)[tid] = make_uint4(0u, 0u, 0u, 0u);
    ((uint4*)Ks)[256 + tid] = make_uint4(0u, 0u, 0u, 0u);
    __syncthreads();

    const int qrow0 = qt * 128 + w * 32;

    s16x8 qf[2][2];
#pragma unroll
    for (int n = 0; n < 2; ++n) {
        const size_t rb = (size_t)(b * 512 + qrow0 + 16 * n + lr) * 2304 + h * 48 + 8 * g;
        qf[n][0] = *(const s16x8*)(qkv + rb);
        qf[n][1] = (g < 2) ? *(const s16x8*)(qkv + rb + 32)
                           : (s16x8){0, 0, 0, 0, 0, 0, 0, 0};
    }

    int p_[3], du_[3];
#pragma unroll
    for (int i = 0; i < 3; ++i) {
        const int idx = tid + 256 * i;
        p_[i] = idx / 24;
        du_[i] = idx % 24;
    }
    uint rk[3][2], rv[3][2];

    auto stage_load = [&](int kv0) {
#pragma unroll
        for (int i = 0; i < 3; ++i) {
            const uint* s0 = qkvu + (size_t)(b * 512 + kv0 + 2 * p_[i]) * 1152
                                  + 192 + h * 24 + du_[i];
            rk[i][0] = s0[0];    rk[i][1] = s0[1152];
            rv[i][0] = s0[192];  rv[i][1] = s0[192 + 1152];
        }
    };
    auto stage_write = [&]() {
#pragma unroll
        for (int i = 0; i < 3; ++i) {
            const int p = p_[i], du = du_[i];
            KsU[(2 * p) * 32 + ((((du >> 2) ^ ((2 * p) & 7)) << 2) | (du & 3))] = rk[i][0];
            KsU[(2 * p + 1) * 32 + ((((du >> 2) ^ ((2 * p + 1) & 7)) << 2) | (du & 3))] = rk[i][1];
            const uint w0 = (rv[i][0] & 0xffffu) | (rv[i][1] << 16);
            const uint w1 = (rv[i][0] >> 16) | (rv[i][1] & 0xffff0000u);
            const int vb = (((p >> 2) ^ (du & 7)) << 2) | (p & 3);
            VtU[(2 * du) * 32 + vb] = w0;
            VtU[(2 * du + 1) * 32 + vb] = w1;
        }
    };

    f32x4 o[2][3];
#pragma unroll
    for (int mq = 0; mq < 2; ++mq)
#pragma unroll
        for (int nd = 0; nd < 3; ++nd) o[mq][nd] = (f32x4){0.f, 0.f, 0.f, 0.f};
    float mrun[2] = {-3.0e38f, -3.0e38f};
    float lsum[2] = {0.f, 0.f};
    float corrv[2];
    const float scale = 0.14433756729740643f; // 1/sqrt(48)

    stage_load(0);
    stage_write();
    __syncthreads();

    for (int t = 0; t < 8; ++t) {
        if (t < 7) stage_load((t + 1) * 64);

        f32x4 sa[4][2];
#pragma unroll
        for (int m = 0; m < 4; ++m)
#pragma unroll
            for (int n = 0; n < 2; ++n) sa[m][n] = (f32x4){0.f, 0.f, 0.f, 0.f};
        __builtin_amdgcn_s_setprio(1);
#pragma unroll
        for (int ks = 0; ks < 2; ++ks)
#pragma unroll
            for (int m = 0; m < 4; ++m) {
                s16x8 kf = *(const s16x8*)&Ks[(16 * m + lr) * 64
                                              + (((g + 4 * ks) ^ (lr & 7)) << 3)];
#pragma unroll
                for (int n = 0; n < 2; ++n)
                    sa[m][n] = __builtin_amdgcn_mfma_f32_16x16x32_bf16(
                        kf, qf[n][ks], sa[m][n], 0, 0, 0);
            }
        __builtin_amdgcn_s_setprio(0);

        bool nogrow[2];
#pragma unroll
        for (int n = 0; n < 2; ++n) {
            float tmax = -3.0e38f;
#pragma unroll
            for (int m = 0; m < 4; ++m)
#pragma unroll
                for (int v = 0; v < 4; ++v) tmax = fmaxf(tmax, sa[m][n][v]);
            tmax = fmaxf(tmax, __shfl_xor(tmax, 16));
            tmax = fmaxf(tmax, __shfl_xor(tmax, 32));
            const float tmax_s = tmax * scale;
            // T13 defer-max: wave-uniform skip of the rescale when no growth
            nogrow[n] = __all(tmax_s <= mrun[n] + 4.f);
            float mnew = nogrow[n] ? mrun[n] : fmaxf(mrun[n], tmax_s);
            float corr = nogrow[n] ? 1.f : __expf(mrun[n] - mnew);
            mrun[n] = mnew;
            float psum = 0.f;
#pragma unroll
            for (int m = 0; m < 4; ++m) {
                float p0 = __expf(fmaf(sa[m][n][0], scale, -mnew));
                float p1 = __expf(fmaf(sa[m][n][1], scale, -mnew));
                float p2 = __expf(fmaf(sa[m][n][2], scale, -mnew));
                float p3 = __expf(fmaf(sa[m][n][3], scale, -mnew));
                psum += (p0 + p1) + (p2 + p3);
                const int base = (16 * n + lr) * 72 + 16 * m + 4 * g;
                *(uint*)&Pl[w][base] = pk2(p0, p1);
                *(uint*)&Pl[w][base + 2] = pk2(p2, p3);
            }
            psum += __shfl_xor(psum, 16);
            psum += __shfl_xor(psum, 32);
            lsum[n] = lsum[n] * corr + psum;
            corrv[n] = corr;
        }

        if (!(nogrow[0] && nogrow[1])) {
#pragma unroll
            for (int mq = 0; mq < 2; ++mq)
#pragma unroll
                for (int nd = 0; nd < 3; ++nd)
#pragma unroll
                    for (int v = 0; v < 4; ++v) o[mq][nd][v] *= corrv[mq];
        }

        __builtin_amdgcn_s_setprio(1);
#pragma unroll
        for (int ks = 0; ks < 2; ++ks) {
            s16x8 vf[3];
#pragma unroll
            for (int nd = 0; nd < 3; ++nd)
                vf[nd] = *(const s16x8*)&Vt[(16 * nd + lr) * 64
                                            + (((g + 4 * ks) ^ (lr >> 1)) << 3)];
#pragma unroll
            for (int mq = 0; mq < 2; ++mq) {
                s16x8 pf = *(const s16x8*)&Pl[w][(16 * mq + lr) * 72 + 8 * g + 32 * ks];
#pragma unroll
                for (int nd = 0; nd < 3; ++nd)
                    o[mq][nd] = __builtin_amdgcn_mfma_f32_16x16x32_bf16(
                        vf[nd], pf, o[mq][nd], 0, 0, 0);
            }
        }
        __builtin_amdgcn_s_setprio(0);
        __syncthreads();
        if (t < 7) stage_write();
        __syncthreads();
    }

#pragma unroll
    for (int mq = 0; mq < 2; ++mq) {
        const float li = 1.f / lsum[mq];
        const int qrow = qrow0 + 16 * mq + lr;
        ushort* dst = xcat + (size_t)(b * 512 + qrow) * 768 + h * 48;
#pragma unroll
        for (int nd = 0; nd < 3; ++nd) {
            uint2 o2;
            o2.x = pk2(o[mq][nd][0] * li, o[mq][nd][1] * li);
            o2.y = pk2(o[mq][nd][2] * li, o[mq][nd][3] * li);
            *(uint2*)(dst + 16 * nd + 4 * g) = o2;
        }
    }
}

// ---------------------------------------------------------------------------
// Column partial sums (bf16 in, fp32 out). grid (32,3,8).
// ---------------------------------------------------------------------------
__global__ __launch_bounds__(256) void colsum(
    const ushort* __restrict__ xcat, float* __restrict__ partial)
{
    const int b = blockIdx.x, ch = blockIdx.y, part = blockIdx.z;
    const int e = ch * 256 + threadIdx.x;
    const int n0 = part * 64;
    float s = 0.f;
    for (int n = 0; n < 64; ++n)
        s += __uint_as_float((uint)xcat[((size_t)(b * 512 + n0 + n)) * 768 + e] << 16);
    partial[((size_t)(b * 8 + part)) * 768 + e] = s;
}

// ---------------------------------------------------------------------------
// Gating, parallel. grid (32 b, 6 j-tiles of 128), 256 thr.
// ---------------------------------------------------------------------------
__global__ __launch_bounds__(256) void alpha_gate(
    const float* __restrict__ partial, const float* __restrict__ Wts,
    const float* __restrict__ bts, float* __restrict__ gate)
{
    const int b = blockIdx.x;
    const int j0 = blockIdx.y * 128;
    __shared__ float av[768];
    __shared__ float psum[2][128];

    for (int i = threadIdx.x; i < 768; i += 256) {
        float s = 0.f;
#pragma unroll
        for (int p = 0; p < 8; ++p)
            s += partial[((size_t)(b * 8 + p)) * 768 + i];
        av[i] = s * (1.0f / 512.0f);
    }
    __syncthreads();

    const int jl = threadIdx.x & 127;
    const int seg = threadIdx.x >> 7;
    const int j = j0 + jl;
    const float* Wp = Wts + (size_t)(seg * 384) * 768 + j;
    const float* avp = av + seg * 384;
    float a0 = 0.f, a1 = 0.f, a2 = 0.f, a3 = 0.f;
    float a4 = 0.f, a5 = 0.f, a6 = 0.f, a7 = 0.f;
#pragma unroll 4
    for (int k = 0; k < 384; k += 8) {
        a0 = fmaf(avp[k + 0], Wp[(size_t)(k + 0) * 768], a0);
        a1 = fmaf(avp[k + 1], Wp[(size_t)(k + 1) * 768], a1);
        a2 = fmaf(avp[k + 2], Wp[(size_t)(k + 2) * 768], a2);
        a3 = fmaf(avp[k + 3], Wp[(size_t)(k + 3) * 768], a3);
        a4 = fmaf(avp[k + 4], Wp[(size_t)(k + 4) * 768], a4);
        a5 = fmaf(avp[k + 5], Wp[(size_t)(k + 5) * 768], a5);
        a6 = fmaf(avp[k + 6], Wp[(size_t)(k + 6) * 768], a6);
        a7 = fmaf(avp[k + 7], Wp[(size_t)(k + 7) * 768], a7);
    }
    psum[seg][jl] = ((a0 + a1) + (a2 + a3)) + ((a4 + a5) + (a6 + a7));
    __syncthreads();

    if (threadIdx.x < 128)
        av[threadIdx.x] = psum[0][threadIdx.x] + psum[1][threadIdx.x]
                        + bts[j0 + threadIdx.x];
    __syncthreads();
    if (threadIdx.x < 64) {
        const int e = (j0 >> 1) + threadIdx.x;
        float x0 = av[2 * threadIdx.x], x1 = av[2 * threadIdx.x + 1];
        float m = fmaxf(x0, x1);
        float e0 = __expf(x0 - m), e1 = __expf(x1 - m);
        float inv = 1.f / (e0 + e1);
        gate[(size_t)b * 768 + e] = e0 * inv;
        gate[(size_t)b * 768 + 384 + e] = e1 * inv;
    }
}

// ---------------------------------------------------------------------------
// xg = bf16(xcat * gate[b]), 8 elems/thread
// ---------------------------------------------------------------------------
__global__ __launch_bounds__(256) void gate_mul(
    const ushort* __restrict__ xcat, const float* __restrict__ gate,
    ushort* __restrict__ xg)
{
    const int i = blockIdx.x * 256 + threadIdx.x;
    const int m = i / 96;
    const int k = (i % 96) * 8;
    const int b = m >> 9;
    uint4 u = ((const uint4*)xcat)[i];
    const float* g = gate + (size_t)b * 768 + k;
    float4 g0 = *(const float4*)g;
    float4 g1 = *(const float4*)(g + 4);
    uint4 o;
    o.x = pk2(lo2f(u.x) * g0.x, hi2f(u.x) * g0.y);
    o.y = pk2(lo2f(u.y) * g0.z, hi2f(u.y) * g0.w);
    o.z = pk2(lo2f(u.z) * g1.x, hi2f(u.z) * g1.y);
    o.w = pk2(lo2f(u.w) * g1.z, hi2f(u.w) * g1.w);
    ((uint4*)xg)[i] = o;
}

// ---------------------------------------------------------------------------
extern "C" void kernel_launch(void* const* d_in, const int* in_sizes, int n_in,
                              void* d_out, int out_size, void* d_ws, size_t ws_size,
                              hipStream_t stream)
{
    const float* x      = (const float*)d_in[0];
    const float* Wqkv_t = (const float*)d_in[1];
    const float* bqkv_t = (const float*)d_in[2];
    const float* Wqkv_s = (const float*)d_in[3];
    const float* bqkv_s = (const float*)d_in[4];
    const float* Wts    = (const float*)d_in[5];
    const float* bts    = (const float*)d_in[6];
    const float* Wfc_t  = (const float*)d_in[7];
    const float* bfc_t  = (const float*)d_in[8];
    const float* Wfc_s  = (const float*)d_in[9];
    const float* bfc_s  = (const float*)d_in[10];
    float* out = (float*)d_out;

    char* w = (char*)d_ws;
    ushort* qkv2   = (ushort*)(w);                 // 16384*2304 bf16 = 75,497,472 B
    ushort* xg     = qkv2;                         // reuse (dead after attn)
    ushort* xcat   = (ushort*)(w + 75497472);      // 16384*768 bf16  = 25,165,824 B
    ushort* xb     = (ushort*)(w + 100663296);     // 16384*768 bf16  = 25,165,824 B
    ushort* wbuf   = (ushort*)(w + 125829120);     // 2304*768 bf16   =  3,538,944 B
    ushort* wbuf2  = (ushort*)(w + 129368064);     // 768*768 bf16    =  1,179,648 B
    float*  partial= (float*)(w + 130547712);      // 32*8*768 f32    =    786,432 B
    float*  gate   = (float*)(w + 131334144);      // 32*768 f32      =     98,304 B
    float*  bias2  = (float*)(w + 131432448);      // 2304 f32

    const dim3 blk256(256);

    // one merged prep launch (convert + bias concat + 4 weight transposes)
    prep<<<dim3(8457), blk256, 0, stream>>>(
        x, xb, bqkv_t, bqkv_s, bias2, Wqkv_t, Wqkv_s, wbuf, Wfc_t, Wfc_s, wbuf2);

    // merged QKV GEMM: [16384 x 2304] = xb @ wbuf^T + bias2
    gemm128p<1, 1><<<dim3(128, 18), blk256, 0, stream>>>(
        xb, wbuf, bias2, nullptr, qkv2, 16384, 2304, 768);

    // fused temporal + spatial attention (one launch, overlapped)
    attn_fused<<<dim3(17408), blk256, 0, stream>>>(qkv2, xcat);

    // gating
    colsum<<<dim3(32, 3, 8), blk256, 0, stream>>>(xcat, partial);
    alpha_gate<<<dim3(32, 6), blk256, 0, stream>>>(partial, Wts, bts, gate);
    gate_mul<<<dim3(6144), blk256, 0, stream>>>(xcat, gate, xg);

    // final GEMM
    gemm128p<0, 2><<<dim3(128, 6), blk256, 0, stream>>>(
        xg, wbuf2, bfc_t, bfc_s, out, 16384, 768, 768);
}